// Round 3
// baseline (665.418 us; speedup 1.0000x reference)
//
#include <hip/hip_runtime.h>
#include <hip/hip_bf16.h>
#include <math.h>

// Problem constants (from reference): D=64, L=2, R=4. N, E derived from sizes.
#define DD 64
#define RREL 4
#define LLAY 2
#define NEG_SLOPE 0.2f
#define EPB 4096   // edges per block in binning passes
#define BSH 10     // bucket shift: 1024 nodes per bucket
#define BSZ 1024

typedef __attribute__((ext_vector_type(8))) short short8;
typedef __attribute__((ext_vector_type(4))) short short4v;
typedef __attribute__((ext_vector_type(4))) float float4v;

__device__ __forceinline__ float lrelu(float x) { return x > 0.f ? x : NEG_SLOPE * x; }

// fp32 -> bf16 round-to-nearest-even (finite values)
__device__ __forceinline__ unsigned short f2bf(float f) {
    unsigned int u = __float_as_uint(f);
    return (unsigned short)((u + 0x7FFFu + ((u >> 16) & 1u)) >> 16);
}
__device__ __forceinline__ float bf2f(unsigned short u) {
    return __uint_as_float((unsigned int)u << 16);
}

// ---------- small precompute: wsrc/wdst = Wg @ a_src, Wg @ a_dst ----------
__global__ void k_wvec(const float* __restrict__ Wg, const float* __restrict__ asrc,
                       const float* __restrict__ adst, float* __restrict__ wsrc,
                       float* __restrict__ wdst) {
    int idx = blockIdx.x * blockDim.x + threadIdx.x;  // L*R*64 = 512
    if (idx >= LLAY * RREL * DD) return;
    int k = idx & 63;
    int lr = idx >> 6;
    const float* W = Wg + (size_t)lr * DD * DD;
    const float* as = asrc + lr * DD;
    const float* ad = adst + lr * DD;
    float s1 = 0.f, s2 = 0.f;
#pragma unroll
    for (int j = 0; j < DD; j++) {
        float w = W[k * DD + j];
        s1 += w * as[j];
        s2 += w * ad[j];
    }
    wsrc[idx] = s1;
    wdst[idx] = s2;
}

// ---------- weight prep: bf16, transposed [n][k]; W1 k-rows pi-permuted ----------
// pi(n) = (n&15)*4 + (n>>4)  (h-gemm packed-store column permutation)
// pi^-1(f) = (f&3)*16 + (f>>2)
__global__ void k_prep(const float* __restrict__ Wg, const float* __restrict__ W1,
                       const float* __restrict__ W2, unsigned short* __restrict__ WgT,
                       unsigned short* __restrict__ W1T, unsigned short* __restrict__ W2T) {
    int idx = blockIdx.x * blockDim.x + threadIdx.x;
    if (idx < 8 * 4096) {  // WgT[lr][n][k] = Wg[lr][k][n]
        int lr = idx >> 12, rem = idx & 4095, n = rem >> 6, k = rem & 63;
        WgT[idx] = f2bf(Wg[(size_t)lr * 4096 + k * 64 + n]);
    } else if (idx < 32768 + 2 * 64 * 320) {  // W1T[l][n][kk]
        int i = idx - 32768;
        int l = i / 20480, rem = i % 20480, n = rem / 320, kk = rem % 320;
        int src;
        if (kk < 64) src = kk;  // x-slice: unpermuted
        else {
            int r = (kk - 64) >> 6, f = (kk - 64) & 63;
            src = 64 + r * 64 + ((f & 3) * 16) + (f >> 2);  // h-slices: pi^-1
        }
        W1T[i] = f2bf(W1[(size_t)l * 20480 + src * 64 + n]);
    } else if (idx < 32768 + 40960 + 2 * 4096) {  // W2T[l][n][k] = W2[l][k][n]
        int i = idx - 73728;
        int l = i >> 12, rem = i & 4095, n = rem >> 6, k = rem & 63;
        W2T[i] = f2bf(W2[(size_t)l * 4096 + k * 64 + n]);
    }
}

// ---------- copy x into combined[:,0:64] (bf16, stride 320) ----------
__global__ void k_copy_x(const float* __restrict__ x, unsigned short* __restrict__ combined,
                         int N) {
    int i = blockIdx.x * blockDim.x + threadIdx.x;  // N*32 uints
    if (i >= N * 32) return;
    int row = i >> 5, c2 = i & 31;
    float2 v = *(const float2*)(x + (size_t)row * DD + c2 * 2);
    unsigned int p = (unsigned int)f2bf(v.x) | ((unsigned int)f2bf(v.y) << 16);
    *(unsigned int*)(combined + (size_t)row * 320 + c2 * 2) = p;
}

// ---------- zero int buffer ----------
__global__ void k_zero(int* __restrict__ p, int n) {
    int i = blockIdx.x * blockDim.x + threadIdx.x;
    if (i < n) p[i] = 0;
}

// ---------- CSR pass A0: coarse bucket histogram (LDS-privatized) ----------
__global__ __launch_bounds__(256) void k_bhist(const int* __restrict__ edges,
                                               int* __restrict__ btot, int E, int NB) {
    int r = blockIdx.y;
    int e0 = blockIdx.x * EPB;
    int t = threadIdx.x;
    __shared__ int lh[128];
    for (int i = t; i < 128; i += 256) lh[i] = 0;
    __syncthreads();
    const int* dstp = edges + (size_t)r * 2 * E + E;
#pragma unroll
    for (int i = 0; i < EPB / 256; i++) {
        int e = e0 + t + 256 * i;
        if (e < E) atomicAdd(&lh[dstp[e] >> BSH], 1);
    }
    __syncthreads();
    for (int i = t; i < NB; i += 256) {
        int c = lh[i];
        if (c) atomicAdd(&btot[r * NB + i], c);
    }
}

// ---------- CSR pass A1: serial scan of bucket totals (tiny) ----------
__global__ void k_bscan(const int* __restrict__ btot, int* __restrict__ bucketoff,
                        int* __restrict__ bpos, int* __restrict__ csr_ptr, int N, int E, int NB) {
    int r = threadIdx.x;
    if (r >= RREL) return;
    int run = 0;
    for (int b = 0; b < NB; b++) {
        bucketoff[r * (NB + 1) + b] = run;
        bpos[r * NB + b] = run;
        run += btot[r * NB + b];
    }
    bucketoff[r * (NB + 1) + NB] = run;  // == E
    csr_ptr[(size_t)r * (N + 1) + N] = E;
}

// ---------- CSR pass A2: block-aggregated bin scatter (dense writes) ----------
__global__ __launch_bounds__(256) void k_binscatter(const int* __restrict__ edges,
                                                    int* __restrict__ bpos,
                                                    unsigned int* __restrict__ packed, int E,
                                                    int NB) {
    int r = blockIdx.y;
    int e0 = blockIdx.x * EPB;
    int t = threadIdx.x;
    __shared__ int lh[128], lbase[128];
    for (int i = t; i < 128; i += 256) lh[i] = 0;
    __syncthreads();
    const int* srcp = edges + (size_t)r * 2 * E;
    const int* dstp = srcp + E;
    int md[EPB / 256], ms[EPB / 256];
#pragma unroll
    for (int i = 0; i < EPB / 256; i++) {
        int e = e0 + t + 256 * i;
        int d = -1, s = 0;
        if (e < E) {
            d = dstp[e];
            s = srcp[e];
            atomicAdd(&lh[d >> BSH], 1);
        }
        md[i] = d;
        ms[i] = s;
    }
    __syncthreads();
    for (int i = t; i < NB; i += 256) {
        int c = lh[i];
        lbase[i] = c ? atomicAdd(&bpos[r * NB + i], c) : 0;
        lh[i] = 0;
    }
    __syncthreads();
#pragma unroll
    for (int i = 0; i < EPB / 256; i++) {
        if (md[i] >= 0) {
            int b = md[i] >> BSH;
            int p = lbase[b] + atomicAdd(&lh[b], 1);
            packed[(size_t)r * E + p] =
                ((unsigned int)(md[i] & (BSZ - 1)) << 17) | (unsigned int)ms[i];
        }
    }
}

// ---------- CSR pass B: per-bucket counting sort (L2-local) + csr_ptr ----------
__global__ __launch_bounds__(256) void k_bucket_sort(const unsigned int* __restrict__ packed,
                                                     const int* __restrict__ bucketoff,
                                                     int* __restrict__ csr_ptr,
                                                     int* __restrict__ csr_src, int N, int E,
                                                     int NB) {
    int r = blockIdx.y, b = blockIdx.x;
    int t = threadIdx.x;
    __shared__ int pos[BSZ];
    __shared__ int tsum[256];
    int base = bucketoff[r * (NB + 1) + b];
    int cnt = bucketoff[r * (NB + 1) + b + 1] - base;
    const unsigned int* pk = packed + (size_t)r * E + base;
    for (int i = t; i < BSZ; i += 256) pos[i] = 0;
    __syncthreads();
    for (int i = t; i < cnt; i += 256) atomicAdd(&pos[pk[i] >> 17], 1);
    __syncthreads();
    int v[4];
    int s = 0;
#pragma unroll
    for (int i = 0; i < 4; i++) {
        v[i] = pos[t * 4 + i];
        s += v[i];
    }
    tsum[t] = s;
    __syncthreads();
    for (int off = 1; off < 256; off <<= 1) {
        int add = (t >= off) ? tsum[t - off] : 0;
        __syncthreads();
        tsum[t] += add;
        __syncthreads();
    }
    int run = tsum[t] - s;  // exclusive
    __syncthreads();
#pragma unroll
    for (int i = 0; i < 4; i++) {
        int node_l = t * 4 + i;
        pos[node_l] = run;
        int node = b * BSZ + node_l;
        if (node < N) csr_ptr[(size_t)r * (N + 1) + node] = base + run;
        run += v[i];
    }
    __syncthreads();
    for (int i = t; i < cnt; i += 256) {
        unsigned int p = pk[i];
        int d = p >> 17;
        int sidx = p & 0x1FFFF;
        int loc = atomicAdd(&pos[d], 1);
        csr_src[(size_t)r * E + base + loc] = sidx;
    }
}

// ---------- edge-parallel logit gather: e_edge[j] = as_[csr_src[j]] ----------
// Chain-free, massive MLP; as_ (400KB/relation) is L2-resident.
__global__ __launch_bounds__(256) void k_elog(const int* __restrict__ csr_src,
                                              const float* __restrict__ as4,
                                              float* __restrict__ e_edge, int E, int N) {
    int r = blockIdx.y;
    const int* cs = csr_src + (size_t)r * E;
    const float* as_ = as4 + (size_t)r * N;
    float* ee = e_edge + (size_t)r * E;
    int base = blockIdx.x * 1024 + threadIdx.x;
    int s[4];
#pragma unroll
    for (int u = 0; u < 4; u++) {
        int e = base + u * 256;
        s[u] = (e < E) ? cs[e] : 0;
    }
#pragma unroll
    for (int u = 0; u < 4; u++) {
        int e = base + u * 256;
        if (e < E) ee[e] = as_[s[u]];
    }
}

// ======== MFMA GEMM kernels: M-tile 256 (4 waves x 64 rows), N=64, 16x16x32 bf16 ========

// ---------- fused h-gemm: h_r = X@Wg_r (bf16, pi-packed), as/ad = X@wvec ----------
__global__ __launch_bounds__(256, 3) void k_hgemm(const unsigned short* __restrict__ X,
                                                  const unsigned short* __restrict__ WgTl,
                                                  const float* __restrict__ wsrcl,
                                                  const float* __restrict__ wdstl,
                                                  unsigned short* __restrict__ h4,
                                                  float* __restrict__ as4,
                                                  float* __restrict__ ad4, int N) {
    __shared__ __align__(16) unsigned short Xb[256][72];
    __shared__ __align__(16) unsigned short Wb[64][72];
    __shared__ float wsS[4][64], wdS[4][64];
    int tid = threadIdx.x, wave = tid >> 6, lane = tid & 63;
    int l15 = lane & 15, q = lane >> 4;
    int row0 = blockIdx.x * 256;
#pragma unroll
    for (int i = 0; i < 8; i++) {
        int f = tid + 256 * i;
        int rr = f >> 3, seg = f & 7;
        int grow = row0 + rr;
        short8 v = (short8){0, 0, 0, 0, 0, 0, 0, 0};
        if (grow < N) v = *(const short8*)(X + (size_t)grow * 320 + seg * 8);
        *(short8*)&Xb[rr][seg * 8] = v;
    }
    wsS[tid >> 6][tid & 63] = wsrcl[tid];
    wdS[tid >> 6][tid & 63] = wdstl[tid];
    __syncthreads();
    short8 afr[4][2];
#pragma unroll
    for (int mt = 0; mt < 4; mt++)
#pragma unroll
        for (int ks = 0; ks < 2; ks++)
            afr[mt][ks] = *(const short8*)&Xb[wave * 64 + mt * 16 + l15][ks * 32 + q * 8];
    {
        int grow = row0 + tid;
        float s[4] = {0.f, 0.f, 0.f, 0.f}, d[4] = {0.f, 0.f, 0.f, 0.f};
#pragma unroll
        for (int seg = 0; seg < 8; seg++) {
            short8 v = *(const short8*)&Xb[tid][seg * 8];
#pragma unroll
            for (int j = 0; j < 8; j++) {
                float xv = bf2f((unsigned short)v[j]);
                int k = seg * 8 + j;
#pragma unroll
                for (int r = 0; r < 4; r++) {
                    s[r] += xv * wsS[r][k];
                    d[r] += xv * wdS[r][k];
                }
            }
        }
        if (grow < N) {
#pragma unroll
            for (int r = 0; r < 4; r++) {
                as4[(size_t)r * N + grow] = s[r];
                ad4[(size_t)r * N + grow] = d[r];
            }
        }
    }
    for (int r = 0; r < 4; r++) {
        __syncthreads();
#pragma unroll
        for (int i = 0; i < 2; i++) {
            int f = tid + 256 * i;
            int n = f >> 3, seg = f & 7;
            *(short8*)&Wb[n][seg * 8] = *(const short8*)(WgTl + r * 4096 + n * 64 + seg * 8);
        }
        __syncthreads();
        short8 bfr[4][2];
#pragma unroll
        for (int nt = 0; nt < 4; nt++)
#pragma unroll
            for (int ks = 0; ks < 2; ks++)
                bfr[nt][ks] = *(const short8*)&Wb[nt * 16 + l15][ks * 32 + q * 8];
        float4v acc[4][4];
#pragma unroll
        for (int mt = 0; mt < 4; mt++)
#pragma unroll
            for (int nt = 0; nt < 4; nt++) acc[mt][nt] = (float4v){0.f, 0.f, 0.f, 0.f};
#pragma unroll
        for (int mt = 0; mt < 4; mt++)
#pragma unroll
            for (int nt = 0; nt < 4; nt++) {
                acc[mt][nt] = __builtin_amdgcn_mfma_f32_16x16x32_bf16(afr[mt][0], bfr[nt][0],
                                                                     acc[mt][nt], 0, 0, 0);
                acc[mt][nt] = __builtin_amdgcn_mfma_f32_16x16x32_bf16(afr[mt][1], bfr[nt][1],
                                                                     acc[mt][nt], 0, 0, 0);
            }
        unsigned short* hr = h4 + (size_t)r * N * 64;
#pragma unroll
        for (int mt = 0; mt < 4; mt++) {
            int rowb = row0 + wave * 64 + mt * 16 + q * 4;
#pragma unroll
            for (int reg = 0; reg < 4; reg++) {
                int row = rowb + reg;
                if (row < N) {
                    short4v sv;
                    sv[0] = (short)f2bf(acc[mt][0][reg]);
                    sv[1] = (short)f2bf(acc[mt][1][reg]);
                    sv[2] = (short)f2bf(acc[mt][2][reg]);
                    sv[3] = (short)f2bf(acc[mt][3][reg]);
                    *(short4v*)&hr[(size_t)row * 64 + l15 * 4] = sv;
                }
            }
        }
    }
}

// ---------- W1 gemm: hid = tanh(combined[N,320](bf16) @ W1 + b1), bf16 out ----------
__global__ __launch_bounds__(256, 3) void k_w1gemm(const unsigned short* __restrict__ X,
                                                   const unsigned short* __restrict__ WT,
                                                   const float* __restrict__ bias,
                                                   unsigned short* __restrict__ Y, int N) {
    __shared__ __align__(16) unsigned short Xb[256][72];
    __shared__ __align__(16) unsigned short Wb[64][72];
    int tid = threadIdx.x, wave = tid >> 6, lane = tid & 63;
    int l15 = lane & 15, q = lane >> 4;
    int row0 = blockIdx.x * 256;
    float4v acc[4][4];
#pragma unroll
    for (int mt = 0; mt < 4; mt++)
#pragma unroll
        for (int nt = 0; nt < 4; nt++) acc[mt][nt] = (float4v){0.f, 0.f, 0.f, 0.f};
    for (int kc = 0; kc < 320; kc += 64) {
        __syncthreads();
#pragma unroll
        for (int i = 0; i < 8; i++) {
            int f = tid + 256 * i;
            int rr = f >> 3, seg = f & 7;
            int grow = row0 + rr;
            short8 v = (short8){0, 0, 0, 0, 0, 0, 0, 0};
            if (grow < N) v = *(const short8*)(X + (size_t)grow * 320 + kc + seg * 8);
            *(short8*)&Xb[rr][seg * 8] = v;
        }
#pragma unroll
        for (int i = 0; i < 2; i++) {
            int f = tid + 256 * i;
            int n = f >> 3, seg = f & 7;
            *(short8*)&Wb[n][seg * 8] = *(const short8*)(WT + n * 320 + kc + seg * 8);
        }
        __syncthreads();
        short8 bfr[4][2];
#pragma unroll
        for (int nt = 0; nt < 4; nt++)
#pragma unroll
            for (int ks = 0; ks < 2; ks++)
                bfr[nt][ks] = *(const short8*)&Wb[nt * 16 + l15][ks * 32 + q * 8];
#pragma unroll
        for (int mt = 0; mt < 4; mt++) {
            short8 a0 = *(const short8*)&Xb[wave * 64 + mt * 16 + l15][q * 8];
            short8 a1 = *(const short8*)&Xb[wave * 64 + mt * 16 + l15][32 + q * 8];
#pragma unroll
            for (int nt = 0; nt < 4; nt++) {
                acc[mt][nt] =
                    __builtin_amdgcn_mfma_f32_16x16x32_bf16(a0, bfr[nt][0], acc[mt][nt], 0, 0, 0);
                acc[mt][nt] =
                    __builtin_amdgcn_mfma_f32_16x16x32_bf16(a1, bfr[nt][1], acc[mt][nt], 0, 0, 0);
            }
        }
    }
#pragma unroll
    for (int mt = 0; mt < 4; mt++) {
        int rowb = row0 + wave * 64 + mt * 16 + q * 4;
#pragma unroll
        for (int reg = 0; reg < 4; reg++) {
            int row = rowb + reg;
            if (row < N) {
#pragma unroll
                for (int nt = 0; nt < 4; nt++) {
                    int n = nt * 16 + l15;
                    float v = tanhf(acc[mt][nt][reg] + bias[n]);
                    Y[(size_t)row * 64 + n] = f2bf(v);
                }
            }
        }
    }
}

// ---------- W2 gemm: dest = hid[N,64](bf16) @ W2 + b2; bf16 (layer0) or fp32 out ----------
template <bool BFOUT>
__global__ __launch_bounds__(256, 3) void k_w2gemm(const unsigned short* __restrict__ X,
                                                   const unsigned short* __restrict__ WT,
                                                   const float* __restrict__ bias,
                                                   unsigned short* __restrict__ Ybf,
                                                   float* __restrict__ Yf, int ldy, int N) {
    __shared__ __align__(16) unsigned short Xb[256][72];
    __shared__ __align__(16) unsigned short Wb[64][72];
    int tid = threadIdx.x, wave = tid >> 6, lane = tid & 63;
    int l15 = lane & 15, q = lane >> 4;
    int row0 = blockIdx.x * 256;
#pragma unroll
    for (int i = 0; i < 8; i++) {
        int f = tid + 256 * i;
        int rr = f >> 3, seg = f & 7;
        int grow = row0 + rr;
        short8 v = (short8){0, 0, 0, 0, 0, 0, 0, 0};
        if (grow < N) v = *(const short8*)(X + (size_t)grow * 64 + seg * 8);
        *(short8*)&Xb[rr][seg * 8] = v;
    }
#pragma unroll
    for (int i = 0; i < 2; i++) {
        int f = tid + 256 * i;
        int n = f >> 3, seg = f & 7;
        *(short8*)&Wb[n][seg * 8] = *(const short8*)(WT + n * 64 + seg * 8);
    }
    __syncthreads();
    short8 bfr[4][2];
#pragma unroll
    for (int nt = 0; nt < 4; nt++)
#pragma unroll
        for (int ks = 0; ks < 2; ks++)
            bfr[nt][ks] = *(const short8*)&Wb[nt * 16 + l15][ks * 32 + q * 8];
    float4v acc[4][4];
#pragma unroll
    for (int mt = 0; mt < 4; mt++)
#pragma unroll
        for (int nt = 0; nt < 4; nt++) acc[mt][nt] = (float4v){0.f, 0.f, 0.f, 0.f};
#pragma unroll
    for (int mt = 0; mt < 4; mt++) {
        short8 a0 = *(const short8*)&Xb[wave * 64 + mt * 16 + l15][q * 8];
        short8 a1 = *(const short8*)&Xb[wave * 64 + mt * 16 + l15][32 + q * 8];
#pragma unroll
        for (int nt = 0; nt < 4; nt++) {
            acc[mt][nt] =
                __builtin_amdgcn_mfma_f32_16x16x32_bf16(a0, bfr[nt][0], acc[mt][nt], 0, 0, 0);
            acc[mt][nt] =
                __builtin_amdgcn_mfma_f32_16x16x32_bf16(a1, bfr[nt][1], acc[mt][nt], 0, 0, 0);
        }
    }
#pragma unroll
    for (int mt = 0; mt < 4; mt++) {
        int rowb = row0 + wave * 64 + mt * 16 + q * 4;
#pragma unroll
        for (int reg = 0; reg < 4; reg++) {
            int row = rowb + reg;
            if (row < N) {
#pragma unroll
                for (int nt = 0; nt < 4; nt++) {
                    int n = nt * 16 + l15;
                    float v = acc[mt][nt][reg] + bias[n];
                    if (BFOUT)
                        Ybf[(size_t)row * ldy + n] = f2bf(v);
                    else
                        Yf[(size_t)row * ldy + n] = v;
                }
            }
        }
    }
}

// ---------- full-wave per-node GAT (proven path; rare fallback, bf16 out) ----------
__device__ void gat_node_fullwave(int node, const int* __restrict__ csr_ptr,
                                  const int* __restrict__ csr_src,
                                  const float* __restrict__ e_edge,
                                  const unsigned short* __restrict__ h,
                                  const float* __restrict__ as_,
                                  const float* __restrict__ ad_, float bgv,
                                  unsigned short* __restrict__ out, int ldo, int lane) {
    float adv = ad_[node];
    float e_self = lrelu(as_[node] + adv);
    int beg = csr_ptr[node], end = csr_ptr[node + 1];
    int cnt = end - beg;

    if (cnt <= 64) {
        int s = 0;
        float e_lane = -3.0e38f;
        if (lane < cnt) {
            s = csr_src[beg + lane];
            e_lane = lrelu(e_edge[beg + lane] + adv);
        }
        float m = fmaxf(e_lane, e_self);
#pragma unroll
        for (int off = 32; off; off >>= 1) m = fmaxf(m, __shfl_xor(m, off));
        float p = (lane < cnt) ? expf(e_lane - m) : 0.f;
        float ssum = p;
#pragma unroll
        for (int off = 32; off; off >>= 1) ssum += __shfl_xor(ssum, off);
        float p_self = expf(e_self - m);
        float inv = 1.f / (ssum + p_self);
        float alpha = p * inv;
        float acc = p_self * inv * bf2f(h[(size_t)node * DD + lane]);
        for (int j0 = 0; j0 < cnt; ++j0) {
            int ss = __shfl(s, j0);
            float aa = __shfl(alpha, j0);
            acc += aa * bf2f(h[(size_t)ss * DD + lane]);
        }
        out[(size_t)node * ldo + lane] = f2bf(acc + bgv);
        return;
    }

    float m = e_self;
    for (int j = beg + lane; j < end; j += 64) m = fmaxf(m, lrelu(e_edge[j] + adv));
#pragma unroll
    for (int off = 32; off; off >>= 1) m = fmaxf(m, __shfl_xor(m, off));
    float ssum = 0.f;
    for (int j = beg + lane; j < end; j += 64) ssum += expf(lrelu(e_edge[j] + adv) - m);
#pragma unroll
    for (int off = 32; off; off >>= 1) ssum += __shfl_xor(ssum, off);
    ssum += expf(e_self - m);
    float inv = 1.f / ssum;
    float acc = expf(e_self - m) * inv * bf2f(h[(size_t)node * DD + lane]);
    for (int j0 = beg; j0 < end; j0 += 64) {
        int j = j0 + lane;
        int s = 0;
        float alpha = 0.f;
        if (j < end) {
            s = csr_src[j];
            alpha = expf(lrelu(e_edge[j] + adv) - m) * inv;
        }
        int c = end - j0;
        if (c > 64) c = 64;
        for (int t = 0; t < c; ++t) {
            int ss = __shfl(s, t);
            float aa = __shfl(alpha, t);
            acc += aa * bf2f(h[(size_t)ss * DD + lane]);
        }
    }
    out[(size_t)node * ldo + lane] = f2bf(acc + bgv);
}

// ---------- GAT: 1 node/wave; paired dword gathers + deferred normalization ----------
// Changes vs R2 (theory: per-wave serial chain + per-edge VMEM issue):
//  * deferred normalization: accumulate with raw p = exp(lrelu(e)); the 6-level
//    shuffle reduction (ssum) runs CONCURRENTLY with the gather loop (both
//    depend only on p); single multiply by rcp(ssum) in the epilogue.
//    Mathematically identical up to fp reordering.
//  * paired dword gathers: lanes 0-31 gather edge j's h row as uint (4B/lane),
//    lanes 32-63 edge j+1 -> 1 VMEM + ~7 VALU per TWO edges (same HBM bytes).
//    Cross-half totals combined with one __shfl_xor(,32) pair at the end;
//    self-row contribution + store on half 0 only (no double count).
//  * (s,p) broadcast via LDS int2 ds_read_b64 (half-dependent base, imm offsets).
//  * padded slots (s=0, p=0) gather node 0's L1-hot row with zero weight.
__global__ __launch_bounds__(256) void k_gat(const int* __restrict__ csr_ptr4,
                                             const int* __restrict__ csr_src4,
                                             const float* __restrict__ e_edge4,
                                             const unsigned short* __restrict__ h4,
                                             const float* __restrict__ as4,
                                             const float* __restrict__ ad4,
                                             const float* __restrict__ bg4,
                                             unsigned short* __restrict__ outbase, int ldo,
                                             int N, int E) {
    __shared__ int2 lsa[4][64];
    int lb = blockIdx.x;
    int r = (lb & 7) >> 1;                     // relation -> XCD pair
    int idx = ((lb >> 3) << 1) + (lb & 1);     // block index within relation
    int wave = threadIdx.x >> 6, lane = threadIdx.x & 63;
    int node = idx * 4 + wave;
    if (node >= N) return;

    const int* csr_ptr = csr_ptr4 + (size_t)r * (N + 1);
    const int* csr_src = csr_src4 + (size_t)r * E;
    const float* e_edge = e_edge4 + (size_t)r * E;
    const unsigned short* h = h4 + (size_t)r * N * 64;
    const float* as_ = as4 + (size_t)r * N;
    const float* ad_ = ad4 + (size_t)r * N;
    const float* bg = bg4 + (size_t)r * DD;
    unsigned short* out = outbase + (size_t)64 * r;

    // wave-uniform CSR bounds -> SGPRs (loop bounds + SALU-friendly addressing)
    int beg = __builtin_amdgcn_readfirstlane(csr_ptr[node]);
    int cnt = __builtin_amdgcn_readfirstlane(csr_ptr[node + 1]) - beg;

    float adv = ad_[node];
    float e_self = lrelu(as_[node] + adv);

    if (cnt <= 64) {
        int half = lane >> 5, lh = lane & 31;
        bool in = lane < cnt;
        int s = 0;
        float ev = 0.f;
        if (in) {
            s = csr_src[beg + lane];              // coalesced sequential
            ev = e_edge[beg + lane];
        }
        // unnormalized weight p = exp(lrelu(e)); padding lanes p=0, s=0
        float p = in ? __expf(lrelu(ev + adv)) : 0.f;
        // stage (src, p) for the whole wave immediately (pre-reduction)
        lsa[wave][lane] = make_int2(s, __float_as_int(p));
        float p_self = __expf(e_self);

        const char* hb = (const char*)h;
        unsigned lane4 = (unsigned)(lh << 2);
        // self row (both halves load the same 128B line; used once, on half 0)
        unsigned int hvs = *(const unsigned int*)(hb + (((unsigned)node) << 7) + lane4);

        float ax0 = 0.f, ay0 = 0.f, ax1 = 0.f, ay1 = 0.f;
        const char* lp = (const char*)&lsa[wave][0] + (half << 3);
        for (int j0 = 0; j0 < cnt; j0 += 16) {    // uniform scalar loop (edges)
            const char* wp = lp + j0 * 8;
#pragma unroll
            for (int g = 0; g < 4; g++) {
                if (j0 + g * 4 < cnt) {           // uniform quad guard (4 edges)
#pragma unroll
                    for (int u = 0; u < 2; u++) { // 2 edge-pairs
                        int2 sa = *(const int2*)(wp + (g * 2 + u) * 16);
                        unsigned voff = ((unsigned)sa.x << 7) + lane4;
                        unsigned int hv = *(const unsigned int*)(hb + voff);
                        float pw = __int_as_float(sa.y);
                        if (u) {
                            ax1 += pw * __uint_as_float(hv << 16);
                            ay1 += pw * __uint_as_float(hv & 0xffff0000u);
                        } else {
                            ax0 += pw * __uint_as_float(hv << 16);
                            ay0 += pw * __uint_as_float(hv & 0xffff0000u);
                        }
                    }
                }
            }
        }
        // reduction overlaps the gather latency (depends only on p)
        float ssum = p;
#pragma unroll
        for (int off = 32; off; off >>= 1) ssum += __shfl_xor(ssum, off);
        float inv = __builtin_amdgcn_rcpf(ssum + p_self);

        float accx = ax0 + ax1, accy = ay0 + ay1;
        accx += __shfl_xor(accx, 32);             // combine even/odd edge halves
        accy += __shfl_xor(accy, 32);
        if (half == 0) {
            int f0 = 2 * lh;
            float bx = bg[((f0 & 3) << 4) | (f0 >> 2)];        // pi^-1(f0)
            float by = bg[(((f0 + 1) & 3) << 4) | (f0 >> 2)];  // pi^-1(f0+1)
            float ox = (accx + p_self * __uint_as_float(hvs << 16)) * inv + bx;
            float oy = (accy + p_self * __uint_as_float(hvs & 0xffff0000u)) * inv + by;
            unsigned int pck = (unsigned int)f2bf(ox) | ((unsigned int)f2bf(oy) << 16);
            *(unsigned int*)(out + (size_t)node * ldo + f0) = pck;
        }
        return;
    }

    // rare fallback: strided full-wave path (proven)
    float bgv = bg[((lane & 3) << 4) | (lane >> 2)];
    gat_node_fullwave(node, csr_ptr, csr_src, e_edge, h, as_, ad_, bgv, out, ldo, lane);
}

extern "C" void kernel_launch(void* const* d_in, const int* in_sizes, int n_in,
                              void* d_out, int out_size, void* d_ws, size_t ws_size,
                              hipStream_t stream) {
    const float* x = (const float*)d_in[0];
    const int* edges = (const int*)d_in[1];
    const float* Wg = (const float*)d_in[2];
    const float* a_src = (const float*)d_in[3];
    const float* a_dst = (const float*)d_in[4];
    const float* bg = (const float*)d_in[5];
    const float* W1 = (const float*)d_in[6];
    const float* b1 = (const float*)d_in[7];
    const float* W2 = (const float*)d_in[8];
    const float* b2 = (const float*)d_in[9];
    float* out = (float*)d_out;

    const int N = in_sizes[0] / DD;          // 100000
    const int E = in_sizes[1] / (2 * RREL);  // 1000000
    const int NB = (N + BSZ - 1) >> BSH;     // 98 buckets (requires N <= 131072)

    // workspace layout (256B aligned)
    size_t off = 0;
    auto alloc = [&](size_t bytes) {
        size_t o = off;
        off = (off + bytes + 255) & ~(size_t)255;
        return o;
    };
    char* ws = (char*)d_ws;
    unsigned short* combined = (unsigned short*)(ws + alloc((size_t)N * 320 * 2));  // bf16
    unsigned short* h4 = (unsigned short*)(ws + alloc((size_t)4 * N * 64 * 2));     // also hid
    float* wsrc = (float*)(ws + alloc(LLAY * RREL * DD * 4));
    float* wdst = (float*)(ws + alloc(LLAY * RREL * DD * 4));
    unsigned short* WgT = (unsigned short*)(ws + alloc(8 * 4096 * 2));
    unsigned short* W1T = (unsigned short*)(ws + alloc(2 * 64 * 320 * 2));
    unsigned short* W2T = (unsigned short*)(ws + alloc(2 * 4096 * 2));
    int* btot = (int*)(ws + alloc((size_t)RREL * NB * 4));
    int* bucketoff = (int*)(ws + alloc((size_t)RREL * (NB + 1) * 4));
    int* bpos = (int*)(ws + alloc((size_t)RREL * NB * 4));
    unsigned int* packed = (unsigned int*)(ws + alloc((size_t)RREL * E * 4));  // also as4/ad4
    int* csr_ptr = (int*)(ws + alloc((size_t)RREL * (N + 1) * 4));
    int* csr_src = (int*)(ws + alloc((size_t)RREL * E * 4));
    float* e_edge = (float*)(ws + alloc((size_t)RREL * E * 4));
    (void)ws_size;
    unsigned short* hid = h4;     // h4 dead when hid is produced
    float* as4 = (float*)packed;  // packed dead after CSR build
    float* ad4 = as4 + (size_t)4 * N;

    const int ebblocks = (E + EPB - 1) / EPB;

    // --- preprocessing ---
    k_zero<<<dim3((RREL * NB + 255) / 256), dim3(256), 0, stream>>>(btot, RREL * NB);
    k_wvec<<<dim3(2), dim3(256), 0, stream>>>(Wg, a_src, a_dst, wsrc, wdst);
    k_prep<<<dim3(320), dim3(256), 0, stream>>>(Wg, W1, W2, WgT, W1T, W2T);
    k_copy_x<<<dim3((N * 32 + 255) / 256), dim3(256), 0, stream>>>(x, combined, N);
    k_bhist<<<dim3(ebblocks, RREL), dim3(256), 0, stream>>>(edges, btot, E, NB);
    k_bscan<<<dim3(1), dim3(64), 0, stream>>>(btot, bucketoff, bpos, csr_ptr, N, E, NB);
    k_binscatter<<<dim3(ebblocks, RREL), dim3(256), 0, stream>>>(edges, bpos, packed, E, NB);
    k_bucket_sort<<<dim3(NB, RREL), dim3(256), 0, stream>>>(packed, bucketoff, csr_ptr, csr_src,
                                                            N, E, NB);

    const int gemm_blocks = (N + 255) / 256;
    const int elog_blocks = (E + 1023) / 1024;
    // k_gat: 4 nodes/block (1 node/wave); grid = 8 * ceil(bpr/2) so lb%8
    // encodes {relation pair -> XCD} and covers all (r, idx) pairs.
    const int bpr = (N + 3) / 4;
    const int gat_grid = 8 * ((bpr + 1) / 2);

    for (int l = 0; l < LLAY; l++) {
        k_hgemm<<<dim3(gemm_blocks), dim3(256), 0, stream>>>(
            combined, WgT + (size_t)l * 4 * 4096, wsrc + l * 256, wdst + l * 256, h4, as4, ad4, N);
        k_elog<<<dim3(elog_blocks, RREL), dim3(256), 0, stream>>>(csr_src, as4, e_edge, E, N);
        k_gat<<<dim3(gat_grid), dim3(256), 0, stream>>>(
            csr_ptr, csr_src, e_edge, h4, as4, ad4, bg + (size_t)l * RREL * DD,
            combined + 64, 320, N, E);
        k_w1gemm<<<dim3(gemm_blocks), dim3(256), 0, stream>>>(combined, W1T + (size_t)l * 20480,
                                                              b1 + l * DD, hid, N);
        if (l == LLAY - 1) {
            k_w2gemm<false><<<dim3(gemm_blocks), dim3(256), 0, stream>>>(
                hid, W2T + (size_t)l * 4096, b2 + l * DD, nullptr, out, DD, N);
        } else {
            k_w2gemm<true><<<dim3(gemm_blocks), dim3(256), 0, stream>>>(
                hid, W2T + (size_t)l * 4096, b2 + l * DD, combined, nullptr, 320, N);
        }
    }
}

// Round 4
// 562.280 us; speedup vs baseline: 1.1834x; 1.1834x over previous
//
#include <hip/hip_runtime.h>
#include <hip/hip_bf16.h>
#include <math.h>

// Problem constants (from reference): D=64, L=2, R=4. N, E derived from sizes.
#define DD 64
#define RREL 4
#define LLAY 2
#define NEG_SLOPE 0.2f
#define EPB 4096   // edges per block in binning passes
#define BSH 10     // bucket shift: 1024 nodes per bucket
#define BSZ 1024

typedef __attribute__((ext_vector_type(8))) short short8;
typedef __attribute__((ext_vector_type(4))) short short4v;
typedef __attribute__((ext_vector_type(4))) float float4v;

__device__ __forceinline__ float lrelu(float x) { return x > 0.f ? x : NEG_SLOPE * x; }

// fp32 -> bf16 round-to-nearest-even (finite values)
__device__ __forceinline__ unsigned short f2bf(float f) {
    unsigned int u = __float_as_uint(f);
    return (unsigned short)((u + 0x7FFFu + ((u >> 16) & 1u)) >> 16);
}
__device__ __forceinline__ float bf2f(unsigned short u) {
    return __uint_as_float((unsigned int)u << 16);
}

// ---------- small precompute: wsrc/wdst = Wg @ a_src, Wg @ a_dst ----------
__global__ void k_wvec(const float* __restrict__ Wg, const float* __restrict__ asrc,
                       const float* __restrict__ adst, float* __restrict__ wsrc,
                       float* __restrict__ wdst) {
    int idx = blockIdx.x * blockDim.x + threadIdx.x;  // L*R*64 = 512
    if (idx >= LLAY * RREL * DD) return;
    int k = idx & 63;
    int lr = idx >> 6;
    const float* W = Wg + (size_t)lr * DD * DD;
    const float* as = asrc + lr * DD;
    const float* ad = adst + lr * DD;
    float s1 = 0.f, s2 = 0.f;
#pragma unroll
    for (int j = 0; j < DD; j++) {
        float w = W[k * DD + j];
        s1 += w * as[j];
        s2 += w * ad[j];
    }
    wsrc[idx] = s1;
    wdst[idx] = s2;
}

// ---------- weight prep: bf16, transposed [n][k]; W1 k-rows pi-permuted ----------
// pi(n) = (n&15)*4 + (n>>4)  (h-gemm packed-store column permutation)
// pi^-1(f) = (f&3)*16 + (f>>2)
__global__ void k_prep(const float* __restrict__ Wg, const float* __restrict__ W1,
                       const float* __restrict__ W2, unsigned short* __restrict__ WgT,
                       unsigned short* __restrict__ W1T, unsigned short* __restrict__ W2T) {
    int idx = blockIdx.x * blockDim.x + threadIdx.x;
    if (idx < 8 * 4096) {  // WgT[lr][n][k] = Wg[lr][k][n]
        int lr = idx >> 12, rem = idx & 4095, n = rem >> 6, k = rem & 63;
        WgT[idx] = f2bf(Wg[(size_t)lr * 4096 + k * 64 + n]);
    } else if (idx < 32768 + 2 * 64 * 320) {  // W1T[l][n][kk]
        int i = idx - 32768;
        int l = i / 20480, rem = i % 20480, n = rem / 320, kk = rem % 320;
        int src;
        if (kk < 64) src = kk;  // x-slice: unpermuted
        else {
            int r = (kk - 64) >> 6, f = (kk - 64) & 63;
            src = 64 + r * 64 + ((f & 3) * 16) + (f >> 2);  // h-slices: pi^-1
        }
        W1T[i] = f2bf(W1[(size_t)l * 20480 + src * 64 + n]);
    } else if (idx < 32768 + 40960 + 2 * 4096) {  // W2T[l][n][k] = W2[l][k][n]
        int i = idx - 73728;
        int l = i >> 12, rem = i & 4095, n = rem >> 6, k = rem & 63;
        W2T[i] = f2bf(W2[(size_t)l * 4096 + k * 64 + n]);
    }
}

// ---------- copy x into combined[:,0:64] (bf16, stride 320) ----------
__global__ void k_copy_x(const float* __restrict__ x, unsigned short* __restrict__ combined,
                         int N) {
    int i = blockIdx.x * blockDim.x + threadIdx.x;  // N*32 uints
    if (i >= N * 32) return;
    int row = i >> 5, c2 = i & 31;
    float2 v = *(const float2*)(x + (size_t)row * DD + c2 * 2);
    unsigned int p = (unsigned int)f2bf(v.x) | ((unsigned int)f2bf(v.y) << 16);
    *(unsigned int*)(combined + (size_t)row * 320 + c2 * 2) = p;
}

// ---------- zero int buffer ----------
__global__ void k_zero(int* __restrict__ p, int n) {
    int i = blockIdx.x * blockDim.x + threadIdx.x;
    if (i < n) p[i] = 0;
}

// ---------- CSR pass A0: coarse bucket histogram (LDS-privatized) ----------
__global__ __launch_bounds__(256) void k_bhist(const int* __restrict__ edges,
                                               int* __restrict__ btot, int E, int NB) {
    int r = blockIdx.y;
    int e0 = blockIdx.x * EPB;
    int t = threadIdx.x;
    __shared__ int lh[128];
    for (int i = t; i < 128; i += 256) lh[i] = 0;
    __syncthreads();
    const int* dstp = edges + (size_t)r * 2 * E + E;
#pragma unroll
    for (int i = 0; i < EPB / 256; i++) {
        int e = e0 + t + 256 * i;
        if (e < E) atomicAdd(&lh[dstp[e] >> BSH], 1);
    }
    __syncthreads();
    for (int i = t; i < NB; i += 256) {
        int c = lh[i];
        if (c) atomicAdd(&btot[r * NB + i], c);
    }
}

// ---------- CSR pass A1: serial scan of bucket totals (tiny) ----------
__global__ void k_bscan(const int* __restrict__ btot, int* __restrict__ bucketoff,
                        int* __restrict__ bpos, int* __restrict__ csr_ptr, int N, int E, int NB) {
    int r = threadIdx.x;
    if (r >= RREL) return;
    int run = 0;
    for (int b = 0; b < NB; b++) {
        bucketoff[r * (NB + 1) + b] = run;
        bpos[r * NB + b] = run;
        run += btot[r * NB + b];
    }
    bucketoff[r * (NB + 1) + NB] = run;  // == E
    csr_ptr[(size_t)r * (N + 1) + N] = E;
}

// ---------- CSR pass A2: block-aggregated bin scatter (dense writes) ----------
__global__ __launch_bounds__(256) void k_binscatter(const int* __restrict__ edges,
                                                    int* __restrict__ bpos,
                                                    unsigned int* __restrict__ packed, int E,
                                                    int NB) {
    int r = blockIdx.y;
    int e0 = blockIdx.x * EPB;
    int t = threadIdx.x;
    __shared__ int lh[128], lbase[128];
    for (int i = t; i < 128; i += 256) lh[i] = 0;
    __syncthreads();
    const int* srcp = edges + (size_t)r * 2 * E;
    const int* dstp = srcp + E;
    int md[EPB / 256], ms[EPB / 256];
#pragma unroll
    for (int i = 0; i < EPB / 256; i++) {
        int e = e0 + t + 256 * i;
        int d = -1, s = 0;
        if (e < E) {
            d = dstp[e];
            s = srcp[e];
            atomicAdd(&lh[d >> BSH], 1);
        }
        md[i] = d;
        ms[i] = s;
    }
    __syncthreads();
    for (int i = t; i < NB; i += 256) {
        int c = lh[i];
        lbase[i] = c ? atomicAdd(&bpos[r * NB + i], c) : 0;
        lh[i] = 0;
    }
    __syncthreads();
#pragma unroll
    for (int i = 0; i < EPB / 256; i++) {
        if (md[i] >= 0) {
            int b = md[i] >> BSH;
            int p = lbase[b] + atomicAdd(&lh[b], 1);
            packed[(size_t)r * E + p] =
                ((unsigned int)(md[i] & (BSZ - 1)) << 17) | (unsigned int)ms[i];
        }
    }
}

// ---------- CSR pass B: per-bucket counting sort (L2-local) + csr_ptr ----------
__global__ __launch_bounds__(256) void k_bucket_sort(const unsigned int* __restrict__ packed,
                                                     const int* __restrict__ bucketoff,
                                                     int* __restrict__ csr_ptr,
                                                     int* __restrict__ csr_src, int N, int E,
                                                     int NB) {
    int r = blockIdx.y, b = blockIdx.x;
    int t = threadIdx.x;
    __shared__ int pos[BSZ];
    __shared__ int tsum[256];
    int base = bucketoff[r * (NB + 1) + b];
    int cnt = bucketoff[r * (NB + 1) + b + 1] - base;
    const unsigned int* pk = packed + (size_t)r * E + base;
    for (int i = t; i < BSZ; i += 256) pos[i] = 0;
    __syncthreads();
    for (int i = t; i < cnt; i += 256) atomicAdd(&pos[pk[i] >> 17], 1);
    __syncthreads();
    int v[4];
    int s = 0;
#pragma unroll
    for (int i = 0; i < 4; i++) {
        v[i] = pos[t * 4 + i];
        s += v[i];
    }
    tsum[t] = s;
    __syncthreads();
    for (int off = 1; off < 256; off <<= 1) {
        int add = (t >= off) ? tsum[t - off] : 0;
        __syncthreads();
        tsum[t] += add;
        __syncthreads();
    }
    int run = tsum[t] - s;  // exclusive
    __syncthreads();
#pragma unroll
    for (int i = 0; i < 4; i++) {
        int node_l = t * 4 + i;
        pos[node_l] = run;
        int node = b * BSZ + node_l;
        if (node < N) csr_ptr[(size_t)r * (N + 1) + node] = base + run;
        run += v[i];
    }
    __syncthreads();
    for (int i = t; i < cnt; i += 256) {
        unsigned int p = pk[i];
        int d = p >> 17;
        int sidx = p & 0x1FFFF;
        int loc = atomicAdd(&pos[d], 1);
        csr_src[(size_t)r * E + base + loc] = sidx;
    }
}

// ---------- edge-parallel logit gather: e_edge[j] = as_[csr_src[j]] ----------
// Chain-free, massive MLP; as_ (400KB/relation) is L2-resident.
__global__ __launch_bounds__(256) void k_elog(const int* __restrict__ csr_src,
                                              const float* __restrict__ as4,
                                              float* __restrict__ e_edge, int E, int N) {
    int r = blockIdx.y;
    const int* cs = csr_src + (size_t)r * E;
    const float* as_ = as4 + (size_t)r * N;
    float* ee = e_edge + (size_t)r * E;
    int base = blockIdx.x * 1024 + threadIdx.x;
    int s[4];
#pragma unroll
    for (int u = 0; u < 4; u++) {
        int e = base + u * 256;
        s[u] = (e < E) ? cs[e] : 0;
    }
#pragma unroll
    for (int u = 0; u < 4; u++) {
        int e = base + u * 256;
        if (e < E) ee[e] = as_[s[u]];
    }
}

// ======== MFMA GEMM kernels: M-tile 256 (4 waves x 64 rows), N=64, 16x16x32 bf16 ========

// ---------- fused h-gemm: h_r = X@Wg_r (bf16, pi-packed), as/ad = X@wvec ----------
__global__ __launch_bounds__(256, 3) void k_hgemm(const unsigned short* __restrict__ X,
                                                  const unsigned short* __restrict__ WgTl,
                                                  const float* __restrict__ wsrcl,
                                                  const float* __restrict__ wdstl,
                                                  unsigned short* __restrict__ h4,
                                                  float* __restrict__ as4,
                                                  float* __restrict__ ad4, int N) {
    __shared__ __align__(16) unsigned short Xb[256][72];
    __shared__ __align__(16) unsigned short Wb[64][72];
    __shared__ float wsS[4][64], wdS[4][64];
    int tid = threadIdx.x, wave = tid >> 6, lane = tid & 63;
    int l15 = lane & 15, q = lane >> 4;
    int row0 = blockIdx.x * 256;
#pragma unroll
    for (int i = 0; i < 8; i++) {
        int f = tid + 256 * i;
        int rr = f >> 3, seg = f & 7;
        int grow = row0 + rr;
        short8 v = (short8){0, 0, 0, 0, 0, 0, 0, 0};
        if (grow < N) v = *(const short8*)(X + (size_t)grow * 320 + seg * 8);
        *(short8*)&Xb[rr][seg * 8] = v;
    }
    wsS[tid >> 6][tid & 63] = wsrcl[tid];
    wdS[tid >> 6][tid & 63] = wdstl[tid];
    __syncthreads();
    short8 afr[4][2];
#pragma unroll
    for (int mt = 0; mt < 4; mt++)
#pragma unroll
        for (int ks = 0; ks < 2; ks++)
            afr[mt][ks] = *(const short8*)&Xb[wave * 64 + mt * 16 + l15][ks * 32 + q * 8];
    {
        int grow = row0 + tid;
        float s[4] = {0.f, 0.f, 0.f, 0.f}, d[4] = {0.f, 0.f, 0.f, 0.f};
#pragma unroll
        for (int seg = 0; seg < 8; seg++) {
            short8 v = *(const short8*)&Xb[tid][seg * 8];
#pragma unroll
            for (int j = 0; j < 8; j++) {
                float xv = bf2f((unsigned short)v[j]);
                int k = seg * 8 + j;
#pragma unroll
                for (int r = 0; r < 4; r++) {
                    s[r] += xv * wsS[r][k];
                    d[r] += xv * wdS[r][k];
                }
            }
        }
        if (grow < N) {
#pragma unroll
            for (int r = 0; r < 4; r++) {
                as4[(size_t)r * N + grow] = s[r];
                ad4[(size_t)r * N + grow] = d[r];
            }
        }
    }
    for (int r = 0; r < 4; r++) {
        __syncthreads();
#pragma unroll
        for (int i = 0; i < 2; i++) {
            int f = tid + 256 * i;
            int n = f >> 3, seg = f & 7;
            *(short8*)&Wb[n][seg * 8] = *(const short8*)(WgTl + r * 4096 + n * 64 + seg * 8);
        }
        __syncthreads();
        short8 bfr[4][2];
#pragma unroll
        for (int nt = 0; nt < 4; nt++)
#pragma unroll
            for (int ks = 0; ks < 2; ks++)
                bfr[nt][ks] = *(const short8*)&Wb[nt * 16 + l15][ks * 32 + q * 8];
        float4v acc[4][4];
#pragma unroll
        for (int mt = 0; mt < 4; mt++)
#pragma unroll
            for (int nt = 0; nt < 4; nt++) acc[mt][nt] = (float4v){0.f, 0.f, 0.f, 0.f};
#pragma unroll
        for (int mt = 0; mt < 4; mt++)
#pragma unroll
            for (int nt = 0; nt < 4; nt++) {
                acc[mt][nt] = __builtin_amdgcn_mfma_f32_16x16x32_bf16(afr[mt][0], bfr[nt][0],
                                                                     acc[mt][nt], 0, 0, 0);
                acc[mt][nt] = __builtin_amdgcn_mfma_f32_16x16x32_bf16(afr[mt][1], bfr[nt][1],
                                                                     acc[mt][nt], 0, 0, 0);
            }
        unsigned short* hr = h4 + (size_t)r * N * 64;
#pragma unroll
        for (int mt = 0; mt < 4; mt++) {
            int rowb = row0 + wave * 64 + mt * 16 + q * 4;
#pragma unroll
            for (int reg = 0; reg < 4; reg++) {
                int row = rowb + reg;
                if (row < N) {
                    short4v sv;
                    sv[0] = (short)f2bf(acc[mt][0][reg]);
                    sv[1] = (short)f2bf(acc[mt][1][reg]);
                    sv[2] = (short)f2bf(acc[mt][2][reg]);
                    sv[3] = (short)f2bf(acc[mt][3][reg]);
                    *(short4v*)&hr[(size_t)row * 64 + l15 * 4] = sv;
                }
            }
        }
    }
}

// ---------- W1 gemm: hid = tanh(combined[N,320](bf16) @ W1 + b1), bf16 out ----------
__global__ __launch_bounds__(256, 3) void k_w1gemm(const unsigned short* __restrict__ X,
                                                   const unsigned short* __restrict__ WT,
                                                   const float* __restrict__ bias,
                                                   unsigned short* __restrict__ Y, int N) {
    __shared__ __align__(16) unsigned short Xb[256][72];
    __shared__ __align__(16) unsigned short Wb[64][72];
    int tid = threadIdx.x, wave = tid >> 6, lane = tid & 63;
    int l15 = lane & 15, q = lane >> 4;
    int row0 = blockIdx.x * 256;
    float4v acc[4][4];
#pragma unroll
    for (int mt = 0; mt < 4; mt++)
#pragma unroll
        for (int nt = 0; nt < 4; nt++) acc[mt][nt] = (float4v){0.f, 0.f, 0.f, 0.f};
    for (int kc = 0; kc < 320; kc += 64) {
        __syncthreads();
#pragma unroll
        for (int i = 0; i < 8; i++) {
            int f = tid + 256 * i;
            int rr = f >> 3, seg = f & 7;
            int grow = row0 + rr;
            short8 v = (short8){0, 0, 0, 0, 0, 0, 0, 0};
            if (grow < N) v = *(const short8*)(X + (size_t)grow * 320 + kc + seg * 8);
            *(short8*)&Xb[rr][seg * 8] = v;
        }
#pragma unroll
        for (int i = 0; i < 2; i++) {
            int f = tid + 256 * i;
            int n = f >> 3, seg = f & 7;
            *(short8*)&Wb[n][seg * 8] = *(const short8*)(WT + n * 320 + kc + seg * 8);
        }
        __syncthreads();
        short8 bfr[4][2];
#pragma unroll
        for (int nt = 0; nt < 4; nt++)
#pragma unroll
            for (int ks = 0; ks < 2; ks++)
                bfr[nt][ks] = *(const short8*)&Wb[nt * 16 + l15][ks * 32 + q * 8];
#pragma unroll
        for (int mt = 0; mt < 4; mt++) {
            short8 a0 = *(const short8*)&Xb[wave * 64 + mt * 16 + l15][q * 8];
            short8 a1 = *(const short8*)&Xb[wave * 64 + mt * 16 + l15][32 + q * 8];
#pragma unroll
            for (int nt = 0; nt < 4; nt++) {
                acc[mt][nt] =
                    __builtin_amdgcn_mfma_f32_16x16x32_bf16(a0, bfr[nt][0], acc[mt][nt], 0, 0, 0);
                acc[mt][nt] =
                    __builtin_amdgcn_mfma_f32_16x16x32_bf16(a1, bfr[nt][1], acc[mt][nt], 0, 0, 0);
            }
        }
    }
#pragma unroll
    for (int mt = 0; mt < 4; mt++) {
        int rowb = row0 + wave * 64 + mt * 16 + q * 4;
#pragma unroll
        for (int reg = 0; reg < 4; reg++) {
            int row = rowb + reg;
            if (row < N) {
#pragma unroll
                for (int nt = 0; nt < 4; nt++) {
                    int n = nt * 16 + l15;
                    float v = tanhf(acc[mt][nt][reg] + bias[n]);
                    Y[(size_t)row * 64 + n] = f2bf(v);
                }
            }
        }
    }
}

// ---------- W2 gemm: dest = hid[N,64](bf16) @ W2 + b2; bf16 (layer0) or fp32 out ----------
template <bool BFOUT>
__global__ __launch_bounds__(256, 3) void k_w2gemm(const unsigned short* __restrict__ X,
                                                   const unsigned short* __restrict__ WT,
                                                   const float* __restrict__ bias,
                                                   unsigned short* __restrict__ Ybf,
                                                   float* __restrict__ Yf, int ldy, int N) {
    __shared__ __align__(16) unsigned short Xb[256][72];
    __shared__ __align__(16) unsigned short Wb[64][72];
    int tid = threadIdx.x, wave = tid >> 6, lane = tid & 63;
    int l15 = lane & 15, q = lane >> 4;
    int row0 = blockIdx.x * 256;
#pragma unroll
    for (int i = 0; i < 8; i++) {
        int f = tid + 256 * i;
        int rr = f >> 3, seg = f & 7;
        int grow = row0 + rr;
        short8 v = (short8){0, 0, 0, 0, 0, 0, 0, 0};
        if (grow < N) v = *(const short8*)(X + (size_t)grow * 64 + seg * 8);
        *(short8*)&Xb[rr][seg * 8] = v;
    }
#pragma unroll
    for (int i = 0; i < 2; i++) {
        int f = tid + 256 * i;
        int n = f >> 3, seg = f & 7;
        *(short8*)&Wb[n][seg * 8] = *(const short8*)(WT + n * 64 + seg * 8);
    }
    __syncthreads();
    short8 bfr[4][2];
#pragma unroll
    for (int nt = 0; nt < 4; nt++)
#pragma unroll
        for (int ks = 0; ks < 2; ks++)
            bfr[nt][ks] = *(const short8*)&Wb[nt * 16 + l15][ks * 32 + q * 8];
    float4v acc[4][4];
#pragma unroll
    for (int mt = 0; mt < 4; mt++)
#pragma unroll
        for (int nt = 0; nt < 4; nt++) acc[mt][nt] = (float4v){0.f, 0.f, 0.f, 0.f};
#pragma unroll
    for (int mt = 0; mt < 4; mt++) {
        short8 a0 = *(const short8*)&Xb[wave * 64 + mt * 16 + l15][q * 8];
        short8 a1 = *(const short8*)&Xb[wave * 64 + mt * 16 + l15][32 + q * 8];
#pragma unroll
        for (int nt = 0; nt < 4; nt++) {
            acc[mt][nt] =
                __builtin_amdgcn_mfma_f32_16x16x32_bf16(a0, bfr[nt][0], acc[mt][nt], 0, 0, 0);
            acc[mt][nt] =
                __builtin_amdgcn_mfma_f32_16x16x32_bf16(a1, bfr[nt][1], acc[mt][nt], 0, 0, 0);
        }
    }
#pragma unroll
    for (int mt = 0; mt < 4; mt++) {
        int rowb = row0 + wave * 64 + mt * 16 + q * 4;
#pragma unroll
        for (int reg = 0; reg < 4; reg++) {
            int row = rowb + reg;
            if (row < N) {
#pragma unroll
                for (int nt = 0; nt < 4; nt++) {
                    int n = nt * 16 + l15;
                    float v = acc[mt][nt][reg] + bias[n];
                    if (BFOUT)
                        Ybf[(size_t)row * ldy + n] = f2bf(v);
                    else
                        Yf[(size_t)row * ldy + n] = v;
                }
            }
        }
    }
}

// ---------- full-wave per-node GAT (proven path; rare fallback, bf16 out) ----------
__device__ void gat_node_fullwave(int node, const int* __restrict__ csr_ptr,
                                  const int* __restrict__ csr_src,
                                  const float* __restrict__ e_edge,
                                  const unsigned short* __restrict__ h,
                                  const float* __restrict__ as_,
                                  const float* __restrict__ ad_, float bgv,
                                  unsigned short* __restrict__ out, int ldo, int lane) {
    float adv = ad_[node];
    float e_self = lrelu(as_[node] + adv);
    int beg = csr_ptr[node], end = csr_ptr[node + 1];
    int cnt = end - beg;

    if (cnt <= 64) {
        int s = 0;
        float e_lane = -3.0e38f;
        if (lane < cnt) {
            s = csr_src[beg + lane];
            e_lane = lrelu(e_edge[beg + lane] + adv);
        }
        float m = fmaxf(e_lane, e_self);
#pragma unroll
        for (int off = 32; off; off >>= 1) m = fmaxf(m, __shfl_xor(m, off));
        float p = (lane < cnt) ? expf(e_lane - m) : 0.f;
        float ssum = p;
#pragma unroll
        for (int off = 32; off; off >>= 1) ssum += __shfl_xor(ssum, off);
        float p_self = expf(e_self - m);
        float inv = 1.f / (ssum + p_self);
        float alpha = p * inv;
        float acc = p_self * inv * bf2f(h[(size_t)node * DD + lane]);
        for (int j0 = 0; j0 < cnt; ++j0) {
            int ss = __shfl(s, j0);
            float aa = __shfl(alpha, j0);
            acc += aa * bf2f(h[(size_t)ss * DD + lane]);
        }
        out[(size_t)node * ldo + lane] = f2bf(acc + bgv);
        return;
    }

    float m = e_self;
    for (int j = beg + lane; j < end; j += 64) m = fmaxf(m, lrelu(e_edge[j] + adv));
#pragma unroll
    for (int off = 32; off; off >>= 1) m = fmaxf(m, __shfl_xor(m, off));
    float ssum = 0.f;
    for (int j = beg + lane; j < end; j += 64) ssum += expf(lrelu(e_edge[j] + adv) - m);
#pragma unroll
    for (int off = 32; off; off >>= 1) ssum += __shfl_xor(ssum, off);
    ssum += expf(e_self - m);
    float inv = 1.f / ssum;
    float acc = expf(e_self - m) * inv * bf2f(h[(size_t)node * DD + lane]);
    for (int j0 = beg; j0 < end; j0 += 64) {
        int j = j0 + lane;
        int s = 0;
        float alpha = 0.f;
        if (j < end) {
            s = csr_src[j];
            alpha = expf(lrelu(e_edge[j] + adv) - m) * inv;
        }
        int c = end - j0;
        if (c > 64) c = 64;
        for (int t = 0; t < c; ++t) {
            int ss = __shfl(s, t);
            float aa = __shfl(alpha, t);
            acc += aa * bf2f(h[(size_t)ss * DD + lane]);
        }
    }
    out[(size_t)node * ldo + lane] = f2bf(acc + bgv);
}

// ---------- GAT: 2 nodes/wave, halves fully independent; LDS (s,p) broadcast ----------
// Changes vs R2/R3 post-mortem (R3's paired-dword gathers regressed: same L1
// transactions, extra epilogue; R2's residual cost is ~40% per-wave FIXED
// overhead at 1 node/wave):
//  * 2 nodes/wave (half = node), 32 feature-lanes each, 2 features/lane.
//    Wave count halves; prologue/reduction/epilogue amortized over 2 nodes.
//  * gather loop runs vmax = max(cntA,cntB) slots; ONE instruction per slot
//    serves both nodes (2 rows = 2 segments, same L1 transaction count as
//    R2's 1-row/instruction). ~35% fewer gather instructions than R2
//    (max vs sum over paired Poisson(10) degrees).
//  * NO cross-half transport at all: each half has its own LDS segment
//    lsa[wave][half][slot], own 5-level __shfl_xor reduction (offsets<=16),
//    own dword store. (The R0-era transport/race class is structurally gone.)
//  * deferred normalization kept: stage raw p = __expf(lrelu(e)); reduction
//    placed AFTER gather-issue so it overlaps the memory wait; one rcp at end.
//  * padded slots (s=0, p=0): gather node 0's L1-hot row with zero weight.
__global__ __launch_bounds__(256) void k_gat(const int* __restrict__ csr_ptr4,
                                             const int* __restrict__ csr_src4,
                                             const float* __restrict__ e_edge4,
                                             const unsigned short* __restrict__ h4,
                                             const float* __restrict__ as4,
                                             const float* __restrict__ ad4,
                                             const float* __restrict__ bg4,
                                             unsigned short* __restrict__ outbase, int ldo,
                                             int N, int E) {
    __shared__ int2 lsa[4][2][32];
    int lb = blockIdx.x;
    int r = (lb & 7) >> 1;                     // relation -> XCD pair
    int idx = ((lb >> 3) << 1) + (lb & 1);     // block index within relation
    int wave = threadIdx.x >> 6, lane = threadIdx.x & 63;
    int half = lane >> 5, lh = lane & 31;
    int nodeA = idx * 8 + wave * 2;            // 8 nodes per block
    if (nodeA >= N) return;
    int node = nodeA + half;
    bool act = node < N;

    const int* csr_ptr = csr_ptr4 + (size_t)r * (N + 1);
    const int* csr_src = csr_src4 + (size_t)r * E;
    const float* e_edge = e_edge4 + (size_t)r * E;
    const unsigned short* h = h4 + (size_t)r * N * 64;
    const float* as_ = as4 + (size_t)r * N;
    const float* ad_ = ad4 + (size_t)r * N;
    const float* bg = bg4 + (size_t)r * DD;
    unsigned short* out = outbase + (size_t)64 * r;

    int beg = 0, cnt = 0;
    if (act) {
        beg = csr_ptr[node];
        cnt = csr_ptr[node + 1] - beg;
    }
    int vmax = __builtin_amdgcn_readfirstlane(max(cnt, __shfl_xor(cnt, 32)));

    if (vmax <= 32) {
        bool in = lh < cnt;                    // implies act (cnt=0 otherwise)
        int s = 0;
        float ev = 0.f;
        if (in) {
            s = csr_src[beg + lh];             // coalesced sequential (per half)
            ev = e_edge[beg + lh];
        }
        float adv = act ? ad_[node] : 0.f;
        float e_self = act ? lrelu(as_[node] + adv) : 0.f;
        // unnormalized weight p = exp(lrelu(e)); padding lanes p=0, s=0
        float p = in ? __expf(lrelu(ev + adv)) : 0.f;
        lsa[wave][half][lh] = make_int2(s, __float_as_int(p));
        float p_self = __expf(e_self);

        const char* hb = (const char*)h;
        unsigned lane4 = (unsigned)(lh << 2);
        unsigned int hvs = 0;
        if (act) hvs = *(const unsigned int*)(hb + (((unsigned)node) << 7) + lane4);

        float ax0 = 0.f, ay0 = 0.f, ax1 = 0.f, ay1 = 0.f;
        const int2* lp = &lsa[wave][half][0];
        for (int j0 = 0; j0 < vmax; j0 += 8) {     // uniform scalar loop
#pragma unroll
            for (int g = 0; g < 2; g++) {
                if (j0 + g * 4 < vmax) {           // uniform quad guard
#pragma unroll
                    for (int u = 0; u < 4; u++) {
                        int2 sa = lp[j0 + g * 4 + u];  // ds_read_b64, imm offset
                        unsigned voff = ((unsigned)sa.x << 7) + lane4;
                        unsigned int hv = *(const unsigned int*)(hb + voff);
                        float pw = __int_as_float(sa.y);
                        if (u & 1) {
                            ax1 += pw * __uint_as_float(hv << 16);
                            ay1 += pw * __uint_as_float(hv & 0xffff0000u);
                        } else {
                            ax0 += pw * __uint_as_float(hv << 16);
                            ay0 += pw * __uint_as_float(hv & 0xffff0000u);
                        }
                    }
                }
            }
        }
        // 5-level within-half reduction; overlaps the gather waits
        float ssum = p;
#pragma unroll
        for (int off = 16; off; off >>= 1) ssum += __shfl_xor(ssum, off);
        float inv = __builtin_amdgcn_rcpf(ssum + p_self);

        if (act) {
            int f0 = 2 * lh;
            float bx = bg[((f0 & 3) << 4) | (f0 >> 2)];        // pi^-1(f0)
            float by = bg[(((f0 + 1) & 3) << 4) | (f0 >> 2)];  // pi^-1(f0+1)
            float ox = (ax0 + ax1 + p_self * __uint_as_float(hvs << 16)) * inv + bx;
            float oy = (ay0 + ay1 + p_self * __uint_as_float(hvs & 0xffff0000u)) * inv + by;
            unsigned int pck = (unsigned int)f2bf(ox) | ((unsigned int)f2bf(oy) << 16);
            *(unsigned int*)(out + (size_t)node * ldo + f0) = pck;
        }
        return;
    }

    // rare fallback: whole wave handles each node sequentially (proven path)
    float bgv = bg[((lane & 3) << 4) | (lane >> 2)];
    if (nodeA < N)
        gat_node_fullwave(nodeA, csr_ptr, csr_src, e_edge, h, as_, ad_, bgv, out, ldo, lane);
    if (nodeA + 1 < N)
        gat_node_fullwave(nodeA + 1, csr_ptr, csr_src, e_edge, h, as_, ad_, bgv, out, ldo, lane);
}

extern "C" void kernel_launch(void* const* d_in, const int* in_sizes, int n_in,
                              void* d_out, int out_size, void* d_ws, size_t ws_size,
                              hipStream_t stream) {
    const float* x = (const float*)d_in[0];
    const int* edges = (const int*)d_in[1];
    const float* Wg = (const float*)d_in[2];
    const float* a_src = (const float*)d_in[3];
    const float* a_dst = (const float*)d_in[4];
    const float* bg = (const float*)d_in[5];
    const float* W1 = (const float*)d_in[6];
    const float* b1 = (const float*)d_in[7];
    const float* W2 = (const float*)d_in[8];
    const float* b2 = (const float*)d_in[9];
    float* out = (float*)d_out;

    const int N = in_sizes[0] / DD;          // 100000
    const int E = in_sizes[1] / (2 * RREL);  // 1000000
    const int NB = (N + BSZ - 1) >> BSH;     // 98 buckets (requires N <= 131072)

    // workspace layout (256B aligned)
    size_t off = 0;
    auto alloc = [&](size_t bytes) {
        size_t o = off;
        off = (off + bytes + 255) & ~(size_t)255;
        return o;
    };
    char* ws = (char*)d_ws;
    unsigned short* combined = (unsigned short*)(ws + alloc((size_t)N * 320 * 2));  // bf16
    unsigned short* h4 = (unsigned short*)(ws + alloc((size_t)4 * N * 64 * 2));     // also hid
    float* wsrc = (float*)(ws + alloc(LLAY * RREL * DD * 4));
    float* wdst = (float*)(ws + alloc(LLAY * RREL * DD * 4));
    unsigned short* WgT = (unsigned short*)(ws + alloc(8 * 4096 * 2));
    unsigned short* W1T = (unsigned short*)(ws + alloc(2 * 64 * 320 * 2));
    unsigned short* W2T = (unsigned short*)(ws + alloc(2 * 4096 * 2));
    int* btot = (int*)(ws + alloc((size_t)RREL * NB * 4));
    int* bucketoff = (int*)(ws + alloc((size_t)RREL * (NB + 1) * 4));
    int* bpos = (int*)(ws + alloc((size_t)RREL * NB * 4));
    unsigned int* packed = (unsigned int*)(ws + alloc((size_t)RREL * E * 4));  // also as4/ad4
    int* csr_ptr = (int*)(ws + alloc((size_t)RREL * (N + 1) * 4));
    int* csr_src = (int*)(ws + alloc((size_t)RREL * E * 4));
    float* e_edge = (float*)(ws + alloc((size_t)RREL * E * 4));
    (void)ws_size;
    unsigned short* hid = h4;     // h4 dead when hid is produced
    float* as4 = (float*)packed;  // packed dead after CSR build
    float* ad4 = as4 + (size_t)4 * N;

    const int ebblocks = (E + EPB - 1) / EPB;

    // --- preprocessing ---
    k_zero<<<dim3((RREL * NB + 255) / 256), dim3(256), 0, stream>>>(btot, RREL * NB);
    k_wvec<<<dim3(2), dim3(256), 0, stream>>>(Wg, a_src, a_dst, wsrc, wdst);
    k_prep<<<dim3(320), dim3(256), 0, stream>>>(Wg, W1, W2, WgT, W1T, W2T);
    k_copy_x<<<dim3((N * 32 + 255) / 256), dim3(256), 0, stream>>>(x, combined, N);
    k_bhist<<<dim3(ebblocks, RREL), dim3(256), 0, stream>>>(edges, btot, E, NB);
    k_bscan<<<dim3(1), dim3(64), 0, stream>>>(btot, bucketoff, bpos, csr_ptr, N, E, NB);
    k_binscatter<<<dim3(ebblocks, RREL), dim3(256), 0, stream>>>(edges, bpos, packed, E, NB);
    k_bucket_sort<<<dim3(NB, RREL), dim3(256), 0, stream>>>(packed, bucketoff, csr_ptr, csr_src,
                                                            N, E, NB);

    const int gemm_blocks = (N + 255) / 256;
    const int elog_blocks = (E + 1023) / 1024;
    // k_gat: 8 nodes/block (2 nodes/wave); grid = 8 * ceil(bpr/2) so lb%8
    // encodes {relation pair -> XCD} and covers all (r, idx) pairs.
    const int bpr = (N + 7) / 8;
    const int gat_grid = 8 * ((bpr + 1) / 2);

    for (int l = 0; l < LLAY; l++) {
        k_hgemm<<<dim3(gemm_blocks), dim3(256), 0, stream>>>(
            combined, WgT + (size_t)l * 4 * 4096, wsrc + l * 256, wdst + l * 256, h4, as4, ad4, N);
        k_elog<<<dim3(elog_blocks, RREL), dim3(256), 0, stream>>>(csr_src, as4, e_edge, E, N);
        k_gat<<<dim3(gat_grid), dim3(256), 0, stream>>>(
            csr_ptr, csr_src, e_edge, h4, as4, ad4, bg + (size_t)l * RREL * DD,
            combined + 64, 320, N, E);
        k_w1gemm<<<dim3(gemm_blocks), dim3(256), 0, stream>>>(combined, W1T + (size_t)l * 20480,
                                                              b1 + l * DD, hid, N);
        if (l == LLAY - 1) {
            k_w2gemm<false><<<dim3(gemm_blocks), dim3(256), 0, stream>>>(
                hid, W2T + (size_t)l * 4096, b2 + l * DD, nullptr, out, DD, N);
        } else {
            k_w2gemm<true><<<dim3(gemm_blocks), dim3(256), 0, stream>>>(
                hid, W2T + (size_t)l * 4096, b2 + l * DD, combined, nullptr, 320, N);
        }
    }
}

// Round 6
// 504.330 us; speedup vs baseline: 1.3194x; 1.1149x over previous
//
#include <hip/hip_runtime.h>
#include <hip/hip_bf16.h>
#include <math.h>

// Problem constants (from reference): D=64, L=2, R=4. N, E derived from sizes.
#define DD 64
#define RREL 4
#define LLAY 2
#define NEG_SLOPE 0.2f
#define EPB 4096   // edges per block in binning passes
#define BSH 10     // bucket shift: 1024 nodes per bucket
#define BSZ 1024

typedef __attribute__((ext_vector_type(8))) short short8;
typedef __attribute__((ext_vector_type(4))) short short4v;
typedef __attribute__((ext_vector_type(4))) float float4v;

__device__ __forceinline__ float lrelu(float x) { return x > 0.f ? x : NEG_SLOPE * x; }

// fp32 -> bf16 round-to-nearest-even (finite values)
__device__ __forceinline__ unsigned short f2bf(float f) {
    unsigned int u = __float_as_uint(f);
    return (unsigned short)((u + 0x7FFFu + ((u >> 16) & 1u)) >> 16);
}
__device__ __forceinline__ float bf2f(unsigned short u) {
    return __uint_as_float((unsigned int)u << 16);
}

// ---------- small precompute: wsrc/wdst = Wg @ a_src, Wg @ a_dst ----------
__global__ void k_wvec(const float* __restrict__ Wg, const float* __restrict__ asrc,
                       const float* __restrict__ adst, float* __restrict__ wsrc,
                       float* __restrict__ wdst) {
    int idx = blockIdx.x * blockDim.x + threadIdx.x;  // L*R*64 = 512
    if (idx >= LLAY * RREL * DD) return;
    int k = idx & 63;
    int lr = idx >> 6;
    const float* W = Wg + (size_t)lr * DD * DD;
    const float* as = asrc + lr * DD;
    const float* ad = adst + lr * DD;
    float s1 = 0.f, s2 = 0.f;
#pragma unroll
    for (int j = 0; j < DD; j++) {
        float w = W[k * DD + j];
        s1 += w * as[j];
        s2 += w * ad[j];
    }
    wsrc[idx] = s1;
    wdst[idx] = s2;
}

// ---------- weight prep: bf16, transposed [n][k]; W1 k-rows pi-permuted ----------
// pi(n) = (n&15)*4 + (n>>4)  (h-gemm packed-store column permutation)
// pi^-1(f) = (f&3)*16 + (f>>2)
__global__ void k_prep(const float* __restrict__ Wg, const float* __restrict__ W1,
                       const float* __restrict__ W2, unsigned short* __restrict__ WgT,
                       unsigned short* __restrict__ W1T, unsigned short* __restrict__ W2T) {
    int idx = blockIdx.x * blockDim.x + threadIdx.x;
    if (idx < 8 * 4096) {  // WgT[lr][n][k] = Wg[lr][k][n]
        int lr = idx >> 12, rem = idx & 4095, n = rem >> 6, k = rem & 63;
        WgT[idx] = f2bf(Wg[(size_t)lr * 4096 + k * 64 + n]);
    } else if (idx < 32768 + 2 * 64 * 320) {  // W1T[l][n][kk]
        int i = idx - 32768;
        int l = i / 20480, rem = i % 20480, n = rem / 320, kk = rem % 320;
        int src;
        if (kk < 64) src = kk;  // x-slice: unpermuted
        else {
            int r = (kk - 64) >> 6, f = (kk - 64) & 63;
            src = 64 + r * 64 + ((f & 3) * 16) + (f >> 2);  // h-slices: pi^-1
        }
        W1T[i] = f2bf(W1[(size_t)l * 20480 + src * 64 + n]);
    } else if (idx < 32768 + 40960 + 2 * 4096) {  // W2T[l][n][k] = W2[l][k][n]
        int i = idx - 73728;
        int l = i >> 12, rem = i & 4095, n = rem >> 6, k = rem & 63;
        W2T[i] = f2bf(W2[(size_t)l * 4096 + k * 64 + n]);
    }
}

// ---------- copy x into combined[:,0:64] (bf16, stride 320) ----------
__global__ void k_copy_x(const float* __restrict__ x, unsigned short* __restrict__ combined,
                         int N) {
    int i = blockIdx.x * blockDim.x + threadIdx.x;  // N*32 uints
    if (i >= N * 32) return;
    int row = i >> 5, c2 = i & 31;
    float2 v = *(const float2*)(x + (size_t)row * DD + c2 * 2);
    unsigned int p = (unsigned int)f2bf(v.x) | ((unsigned int)f2bf(v.y) << 16);
    *(unsigned int*)(combined + (size_t)row * 320 + c2 * 2) = p;
}

// ---------- zero int buffer ----------
__global__ void k_zero(int* __restrict__ p, int n) {
    int i = blockIdx.x * blockDim.x + threadIdx.x;
    if (i < n) p[i] = 0;
}

// ---------- CSR pass A0: coarse bucket histogram (LDS-privatized) ----------
__global__ __launch_bounds__(256) void k_bhist(const int* __restrict__ edges,
                                               int* __restrict__ btot, int E, int NB) {
    int r = blockIdx.y;
    int e0 = blockIdx.x * EPB;
    int t = threadIdx.x;
    __shared__ int lh[128];
    for (int i = t; i < 128; i += 256) lh[i] = 0;
    __syncthreads();
    const int* dstp = edges + (size_t)r * 2 * E + E;
#pragma unroll
    for (int i = 0; i < EPB / 256; i++) {
        int e = e0 + t + 256 * i;
        if (e < E) atomicAdd(&lh[dstp[e] >> BSH], 1);
    }
    __syncthreads();
    for (int i = t; i < NB; i += 256) {
        int c = lh[i];
        if (c) atomicAdd(&btot[r * NB + i], c);
    }
}

// ---------- CSR pass A1: serial scan of bucket totals (tiny) ----------
__global__ void k_bscan(const int* __restrict__ btot, int* __restrict__ bucketoff,
                        int* __restrict__ bpos, int* __restrict__ csr_ptr, int N, int E, int NB) {
    int r = threadIdx.x;
    if (r >= RREL) return;
    int run = 0;
    for (int b = 0; b < NB; b++) {
        bucketoff[r * (NB + 1) + b] = run;
        bpos[r * NB + b] = run;
        run += btot[r * NB + b];
    }
    bucketoff[r * (NB + 1) + NB] = run;  // == E
    csr_ptr[(size_t)r * (N + 1) + N] = E;
}

// ---------- CSR pass A2: block-aggregated bin scatter (dense writes) ----------
__global__ __launch_bounds__(256) void k_binscatter(const int* __restrict__ edges,
                                                    int* __restrict__ bpos,
                                                    unsigned int* __restrict__ packed, int E,
                                                    int NB) {
    int r = blockIdx.y;
    int e0 = blockIdx.x * EPB;
    int t = threadIdx.x;
    __shared__ int lh[128], lbase[128];
    for (int i = t; i < 128; i += 256) lh[i] = 0;
    __syncthreads();
    const int* srcp = edges + (size_t)r * 2 * E;
    const int* dstp = srcp + E;
    int md[EPB / 256], ms[EPB / 256];
#pragma unroll
    for (int i = 0; i < EPB / 256; i++) {
        int e = e0 + t + 256 * i;
        int d = -1, s = 0;
        if (e < E) {
            d = dstp[e];
            s = srcp[e];
            atomicAdd(&lh[d >> BSH], 1);
        }
        md[i] = d;
        ms[i] = s;
    }
    __syncthreads();
    for (int i = t; i < NB; i += 256) {
        int c = lh[i];
        lbase[i] = c ? atomicAdd(&bpos[r * NB + i], c) : 0;
        lh[i] = 0;
    }
    __syncthreads();
#pragma unroll
    for (int i = 0; i < EPB / 256; i++) {
        if (md[i] >= 0) {
            int b = md[i] >> BSH;
            int p = lbase[b] + atomicAdd(&lh[b], 1);
            packed[(size_t)r * E + p] =
                ((unsigned int)(md[i] & (BSZ - 1)) << 17) | (unsigned int)ms[i];
        }
    }
}

// ---------- CSR pass B: per-bucket counting sort (L2-local) + csr_ptr ----------
__global__ __launch_bounds__(256) void k_bucket_sort(const unsigned int* __restrict__ packed,
                                                     const int* __restrict__ bucketoff,
                                                     int* __restrict__ csr_ptr,
                                                     int* __restrict__ csr_src, int N, int E,
                                                     int NB) {
    int r = blockIdx.y, b = blockIdx.x;
    int t = threadIdx.x;
    __shared__ int pos[BSZ];
    __shared__ int tsum[256];
    int base = bucketoff[r * (NB + 1) + b];
    int cnt = bucketoff[r * (NB + 1) + b + 1] - base;
    const unsigned int* pk = packed + (size_t)r * E + base;
    for (int i = t; i < BSZ; i += 256) pos[i] = 0;
    __syncthreads();
    for (int i = t; i < cnt; i += 256) atomicAdd(&pos[pk[i] >> 17], 1);
    __syncthreads();
    int v[4];
    int s = 0;
#pragma unroll
    for (int i = 0; i < 4; i++) {
        v[i] = pos[t * 4 + i];
        s += v[i];
    }
    tsum[t] = s;
    __syncthreads();
    for (int off = 1; off < 256; off <<= 1) {
        int add = (t >= off) ? tsum[t - off] : 0;
        __syncthreads();
        tsum[t] += add;
        __syncthreads();
    }
    int run = tsum[t] - s;  // exclusive
    __syncthreads();
#pragma unroll
    for (int i = 0; i < 4; i++) {
        int node_l = t * 4 + i;
        pos[node_l] = run;
        int node = b * BSZ + node_l;
        if (node < N) csr_ptr[(size_t)r * (N + 1) + node] = base + run;
        run += v[i];
    }
    __syncthreads();
    for (int i = t; i < cnt; i += 256) {
        unsigned int p = pk[i];
        int d = p >> 17;
        int sidx = p & 0x1FFFF;
        int loc = atomicAdd(&pos[d], 1);
        csr_src[(size_t)r * E + base + loc] = sidx;
    }
}

// ======== MFMA GEMM kernels: M-tile 256 (4 waves x 64 rows), N=64, 16x16x32 bf16 ========

// ---------- fused h-gemm: h_r = X@Wg_r (bf16, pi-packed), as/ad = X@wvec ----------
__global__ __launch_bounds__(256, 3) void k_hgemm(const unsigned short* __restrict__ X,
                                                  const unsigned short* __restrict__ WgTl,
                                                  const float* __restrict__ wsrcl,
                                                  const float* __restrict__ wdstl,
                                                  unsigned short* __restrict__ h4,
                                                  float* __restrict__ as4,
                                                  float* __restrict__ ad4, int N) {
    __shared__ __align__(16) unsigned short Xb[256][72];
    __shared__ __align__(16) unsigned short Wb[64][72];
    __shared__ float wsS[4][64], wdS[4][64];
    int tid = threadIdx.x, wave = tid >> 6, lane = tid & 63;
    int l15 = lane & 15, q = lane >> 4;
    int row0 = blockIdx.x * 256;
#pragma unroll
    for (int i = 0; i < 8; i++) {
        int f = tid + 256 * i;
        int rr = f >> 3, seg = f & 7;
        int grow = row0 + rr;
        short8 v = (short8){0, 0, 0, 0, 0, 0, 0, 0};
        if (grow < N) v = *(const short8*)(X + (size_t)grow * 320 + seg * 8);
        *(short8*)&Xb[rr][seg * 8] = v;
    }
    wsS[tid >> 6][tid & 63] = wsrcl[tid];
    wdS[tid >> 6][tid & 63] = wdstl[tid];
    __syncthreads();
    short8 afr[4][2];
#pragma unroll
    for (int mt = 0; mt < 4; mt++)
#pragma unroll
        for (int ks = 0; ks < 2; ks++)
            afr[mt][ks] = *(const short8*)&Xb[wave * 64 + mt * 16 + l15][ks * 32 + q * 8];
    {
        int grow = row0 + tid;
        float s[4] = {0.f, 0.f, 0.f, 0.f}, d[4] = {0.f, 0.f, 0.f, 0.f};
#pragma unroll
        for (int seg = 0; seg < 8; seg++) {
            short8 v = *(const short8*)&Xb[tid][seg * 8];
#pragma unroll
            for (int j = 0; j < 8; j++) {
                float xv = bf2f((unsigned short)v[j]);
                int k = seg * 8 + j;
#pragma unroll
                for (int r = 0; r < 4; r++) {
                    s[r] += xv * wsS[r][k];
                    d[r] += xv * wdS[r][k];
                }
            }
        }
        if (grow < N) {
#pragma unroll
            for (int r = 0; r < 4; r++) {
                as4[(size_t)r * N + grow] = s[r];
                ad4[(size_t)r * N + grow] = d[r];
            }
        }
    }
    for (int r = 0; r < 4; r++) {
        __syncthreads();
#pragma unroll
        for (int i = 0; i < 2; i++) {
            int f = tid + 256 * i;
            int n = f >> 3, seg = f & 7;
            *(short8*)&Wb[n][seg * 8] = *(const short8*)(WgTl + r * 4096 + n * 64 + seg * 8);
        }
        __syncthreads();
        short8 bfr[4][2];
#pragma unroll
        for (int nt = 0; nt < 4; nt++)
#pragma unroll
            for (int ks = 0; ks < 2; ks++)
                bfr[nt][ks] = *(const short8*)&Wb[nt * 16 + l15][ks * 32 + q * 8];
        float4v acc[4][4];
#pragma unroll
        for (int mt = 0; mt < 4; mt++)
#pragma unroll
            for (int nt = 0; nt < 4; nt++) acc[mt][nt] = (float4v){0.f, 0.f, 0.f, 0.f};
#pragma unroll
        for (int mt = 0; mt < 4; mt++)
#pragma unroll
            for (int nt = 0; nt < 4; nt++) {
                acc[mt][nt] = __builtin_amdgcn_mfma_f32_16x16x32_bf16(afr[mt][0], bfr[nt][0],
                                                                     acc[mt][nt], 0, 0, 0);
                acc[mt][nt] = __builtin_amdgcn_mfma_f32_16x16x32_bf16(afr[mt][1], bfr[nt][1],
                                                                     acc[mt][nt], 0, 0, 0);
            }
        unsigned short* hr = h4 + (size_t)r * N * 64;
#pragma unroll
        for (int mt = 0; mt < 4; mt++) {
            int rowb = row0 + wave * 64 + mt * 16 + q * 4;
#pragma unroll
            for (int reg = 0; reg < 4; reg++) {
                int row = rowb + reg;
                if (row < N) {
                    short4v sv;
                    sv[0] = (short)f2bf(acc[mt][0][reg]);
                    sv[1] = (short)f2bf(acc[mt][1][reg]);
                    sv[2] = (short)f2bf(acc[mt][2][reg]);
                    sv[3] = (short)f2bf(acc[mt][3][reg]);
                    *(short4v*)&hr[(size_t)row * 64 + l15 * 4] = sv;
                }
            }
        }
    }
}

// ---------- fused MLP: Y = (tanh(X[N,320]@W1+b1))@W2 + b2; bf16 or fp32 out ----------
// w1 phase identical to old k_w1gemm; tanh result goes to LDS (Xb reuse) instead
// of global hid; w2 phase (64x64) runs in the same block. Saves the 12.8MB hid
// write + 12.8MB read per layer + one launch.
template <bool BFOUT>
__global__ __launch_bounds__(256, 3) void k_mlp(const unsigned short* __restrict__ X,
                                                const unsigned short* __restrict__ W1Tl,
                                                const float* __restrict__ b1,
                                                const unsigned short* __restrict__ W2Tl,
                                                const float* __restrict__ b2,
                                                unsigned short* __restrict__ Ybf,
                                                float* __restrict__ Yf, int ldy, int N) {
    __shared__ __align__(16) unsigned short Xb[256][72];
    __shared__ __align__(16) unsigned short Wb[64][72];
    int tid = threadIdx.x, wave = tid >> 6, lane = tid & 63;
    int l15 = lane & 15, q = lane >> 4;
    int row0 = blockIdx.x * 256;
    float4v acc[4][4];
#pragma unroll
    for (int mt = 0; mt < 4; mt++)
#pragma unroll
        for (int nt = 0; nt < 4; nt++) acc[mt][nt] = (float4v){0.f, 0.f, 0.f, 0.f};
    for (int kc = 0; kc < 320; kc += 64) {
        __syncthreads();
#pragma unroll
        for (int i = 0; i < 8; i++) {
            int f = tid + 256 * i;
            int rr = f >> 3, seg = f & 7;
            int grow = row0 + rr;
            short8 v = (short8){0, 0, 0, 0, 0, 0, 0, 0};
            if (grow < N) v = *(const short8*)(X + (size_t)grow * 320 + kc + seg * 8);
            *(short8*)&Xb[rr][seg * 8] = v;
        }
#pragma unroll
        for (int i = 0; i < 2; i++) {
            int f = tid + 256 * i;
            int n = f >> 3, seg = f & 7;
            *(short8*)&Wb[n][seg * 8] = *(const short8*)(W1Tl + n * 320 + kc + seg * 8);
        }
        __syncthreads();
        short8 bfr[4][2];
#pragma unroll
        for (int nt = 0; nt < 4; nt++)
#pragma unroll
            for (int ks = 0; ks < 2; ks++)
                bfr[nt][ks] = *(const short8*)&Wb[nt * 16 + l15][ks * 32 + q * 8];
#pragma unroll
        for (int mt = 0; mt < 4; mt++) {
            short8 a0 = *(const short8*)&Xb[wave * 64 + mt * 16 + l15][q * 8];
            short8 a1 = *(const short8*)&Xb[wave * 64 + mt * 16 + l15][32 + q * 8];
#pragma unroll
            for (int nt = 0; nt < 4; nt++) {
                acc[mt][nt] =
                    __builtin_amdgcn_mfma_f32_16x16x32_bf16(a0, bfr[nt][0], acc[mt][nt], 0, 0, 0);
                acc[mt][nt] =
                    __builtin_amdgcn_mfma_f32_16x16x32_bf16(a1, bfr[nt][1], acc[mt][nt], 0, 0, 0);
            }
        }
    }
    // tanh epilogue -> LDS (Xb reuse; covers all 256 rows x 64 cols exactly once)
    __syncthreads();
#pragma unroll
    for (int mt = 0; mt < 4; mt++) {
        int rlb = wave * 64 + mt * 16 + q * 4;
#pragma unroll
        for (int reg = 0; reg < 4; reg++) {
#pragma unroll
            for (int nt = 0; nt < 4; nt++) {
                int n = nt * 16 + l15;
                Xb[rlb + reg][n] = f2bf(tanhf(acc[mt][nt][reg] + b1[n]));
            }
        }
    }
    // stage W2 into Wb
#pragma unroll
    for (int i = 0; i < 2; i++) {
        int f = tid + 256 * i;
        int n = f >> 3, seg = f & 7;
        *(short8*)&Wb[n][seg * 8] = *(const short8*)(W2Tl + n * 64 + seg * 8);
    }
    __syncthreads();
    // w2 phase
    short8 bfr[4][2];
#pragma unroll
    for (int nt = 0; nt < 4; nt++)
#pragma unroll
        for (int ks = 0; ks < 2; ks++)
            bfr[nt][ks] = *(const short8*)&Wb[nt * 16 + l15][ks * 32 + q * 8];
    float4v acc2[4][4];
#pragma unroll
    for (int mt = 0; mt < 4; mt++)
#pragma unroll
        for (int nt = 0; nt < 4; nt++) acc2[mt][nt] = (float4v){0.f, 0.f, 0.f, 0.f};
#pragma unroll
    for (int mt = 0; mt < 4; mt++) {
        short8 a0 = *(const short8*)&Xb[wave * 64 + mt * 16 + l15][q * 8];
        short8 a1 = *(const short8*)&Xb[wave * 64 + mt * 16 + l15][32 + q * 8];
#pragma unroll
        for (int nt = 0; nt < 4; nt++) {
            acc2[mt][nt] =
                __builtin_amdgcn_mfma_f32_16x16x32_bf16(a0, bfr[nt][0], acc2[mt][nt], 0, 0, 0);
            acc2[mt][nt] =
                __builtin_amdgcn_mfma_f32_16x16x32_bf16(a1, bfr[nt][1], acc2[mt][nt], 0, 0, 0);
        }
    }
#pragma unroll
    for (int mt = 0; mt < 4; mt++) {
        int rowb = row0 + wave * 64 + mt * 16 + q * 4;
#pragma unroll
        for (int reg = 0; reg < 4; reg++) {
            int row = rowb + reg;
            if (row < N) {
#pragma unroll
                for (int nt = 0; nt < 4; nt++) {
                    int n = nt * 16 + l15;
                    float v = acc2[mt][nt][reg] + b2[n];
                    if (BFOUT)
                        Ybf[(size_t)row * ldy + n] = f2bf(v);
                    else
                        Yf[(size_t)row * ldy + n] = v;
                }
            }
        }
    }
}

// ---------- full-wave per-node GAT (rare fallback; gathers as_ directly) ----------
__device__ void gat_node_fullwave(int node, const int* __restrict__ csr_ptr,
                                  const int* __restrict__ csr_src,
                                  const unsigned short* __restrict__ h,
                                  const float* __restrict__ as_,
                                  const float* __restrict__ ad_, float bgv,
                                  unsigned short* __restrict__ out, int ldo, int lane) {
    float adv = ad_[node];
    float e_self = lrelu(as_[node] + adv);
    int beg = csr_ptr[node], end = csr_ptr[node + 1];
    int cnt = end - beg;

    if (cnt <= 64) {
        int s = 0;
        float e_lane = -3.0e38f;
        if (lane < cnt) {
            s = csr_src[beg + lane];
            e_lane = lrelu(as_[s] + adv);
        }
        float m = fmaxf(e_lane, e_self);
#pragma unroll
        for (int off = 32; off; off >>= 1) m = fmaxf(m, __shfl_xor(m, off));
        float p = (lane < cnt) ? expf(e_lane - m) : 0.f;
        float ssum = p;
#pragma unroll
        for (int off = 32; off; off >>= 1) ssum += __shfl_xor(ssum, off);
        float p_self = expf(e_self - m);
        float inv = 1.f / (ssum + p_self);
        float alpha = p * inv;
        float acc = p_self * inv * bf2f(h[(size_t)node * DD + lane]);
        for (int j0 = 0; j0 < cnt; ++j0) {
            int ss = __shfl(s, j0);
            float aa = __shfl(alpha, j0);
            acc += aa * bf2f(h[(size_t)ss * DD + lane]);
        }
        out[(size_t)node * ldo + lane] = f2bf(acc + bgv);
        return;
    }

    float m = e_self;
    for (int j = beg + lane; j < end; j += 64) m = fmaxf(m, lrelu(as_[csr_src[j]] + adv));
#pragma unroll
    for (int off = 32; off; off >>= 1) m = fmaxf(m, __shfl_xor(m, off));
    float ssum = 0.f;
    for (int j = beg + lane; j < end; j += 64) ssum += expf(lrelu(as_[csr_src[j]] + adv) - m);
#pragma unroll
    for (int off = 32; off; off >>= 1) ssum += __shfl_xor(ssum, off);
    ssum += expf(e_self - m);
    float inv = 1.f / ssum;
    float acc = expf(e_self - m) * inv * bf2f(h[(size_t)node * DD + lane]);
    for (int j0 = beg; j0 < end; j0 += 64) {
        int j = j0 + lane;
        int s = 0;
        float alpha = 0.f;
        if (j < end) {
            s = csr_src[j];
            alpha = expf(lrelu(as_[s] + adv) - m) * inv;
        }
        int c = end - j0;
        if (c > 64) c = 64;
        for (int t = 0; t < c; ++t) {
            int ss = __shfl(s, t);
            float aa = __shfl(alpha, t);
            acc += aa * bf2f(h[(size_t)ss * DD + lane]);
        }
    }
    out[(size_t)node * ldo + lane] = f2bf(acc + bgv);
}

// ---------- GAT: 2 nodes/wave, halves independent; inline as_ gather (no e_edge) ----
// Changes vs R4:
//  * e_edge eliminated (k_elog kernel + 32MB/layer traffic gone): logits are
//    computed inline via as_[s] random 4B gathers. as_ is 400KB/relation and
//    XCD-pair-local -> L2-resident (~200cy).
//  * (s,p) staging SPLIT into lsa_s / lsa_p (provably non-aliasing): s staged
//    immediately after the csr_src load, BEFORE the exp chain -> the compiler
//    can hoist the loop's s ds_reads + h global_load issue ahead of the p
//    write, overlapping the h-gather latency with as_-gather + exp + p-stage.
__global__ __launch_bounds__(256) void k_gat(const int* __restrict__ csr_ptr4,
                                             const int* __restrict__ csr_src4,
                                             const unsigned short* __restrict__ h4,
                                             const float* __restrict__ as4,
                                             const float* __restrict__ ad4,
                                             const float* __restrict__ bg4,
                                             unsigned short* __restrict__ outbase, int ldo,
                                             int N, int E) {
    __shared__ int lsa_s[4][2][32];
    __shared__ float lsa_p[4][2][32];
    int lb = blockIdx.x;
    int r = (lb & 7) >> 1;                     // relation -> XCD pair
    int idx = ((lb >> 3) << 1) + (lb & 1);     // block index within relation
    int wave = threadIdx.x >> 6, lane = threadIdx.x & 63;
    int half = lane >> 5, lh = lane & 31;
    int nodeA = idx * 8 + wave * 2;            // 8 nodes per block
    if (nodeA >= N) return;
    int node = nodeA + half;
    bool act = node < N;

    const int* csr_ptr = csr_ptr4 + (size_t)r * (N + 1);
    const int* csr_src = csr_src4 + (size_t)r * E;
    const unsigned short* h = h4 + (size_t)r * N * 64;
    const float* as_ = as4 + (size_t)r * N;
    const float* ad_ = ad4 + (size_t)r * N;
    const float* bg = bg4 + (size_t)r * DD;
    unsigned short* out = outbase + (size_t)64 * r;

    int beg = 0, cnt = 0;
    if (act) {
        beg = csr_ptr[node];
        cnt = csr_ptr[node + 1] - beg;
    }
    int vmax = __builtin_amdgcn_readfirstlane(max(cnt, __shfl_xor(cnt, 32)));

    if (vmax <= 32) {
        bool in = lh < cnt;                    // implies act (cnt=0 otherwise)
        int s = 0;
        if (in) s = csr_src[beg + lh];         // coalesced sequential (per half)
        lsa_s[wave][half][lh] = s;             // stage s EARLY (padding -> 0)
        float adv = act ? ad_[node] : 0.f;
        float asl = in ? as_[s] : 0.f;         // random 4B gather, L2-resident
        float e_self = act ? lrelu(as_[node] + adv) : 0.f;
        float p = in ? __expf(lrelu(asl + adv)) : 0.f;
        lsa_p[wave][half][lh] = p;             // stage p late (padding -> 0)
        float p_self = __expf(e_self);

        const char* hb = (const char*)h;
        unsigned lane4 = (unsigned)(lh << 2);
        unsigned int hvs = 0;
        if (act) hvs = *(const unsigned int*)(hb + (((unsigned)node) << 7) + lane4);

        float ax0 = 0.f, ay0 = 0.f, ax1 = 0.f, ay1 = 0.f;
        const int* sp = &lsa_s[wave][half][0];
        const float* pp = &lsa_p[wave][half][0];
        for (int j0 = 0; j0 < vmax; j0 += 8) {     // uniform scalar loop
#pragma unroll
            for (int g = 0; g < 2; g++) {
                if (j0 + g * 4 < vmax) {           // uniform quad guard
#pragma unroll
                    for (int u = 0; u < 4; u++) {
                        int sv = sp[j0 + g * 4 + u];       // ds_read_b32 (early)
                        unsigned voff = ((unsigned)sv << 7) + lane4;
                        unsigned int hv = *(const unsigned int*)(hb + voff);
                        float pw = pp[j0 + g * 4 + u];     // ds_read_b32 (late)
                        if (u & 1) {
                            ax1 += pw * __uint_as_float(hv << 16);
                            ay1 += pw * __uint_as_float(hv & 0xffff0000u);
                        } else {
                            ax0 += pw * __uint_as_float(hv << 16);
                            ay0 += pw * __uint_as_float(hv & 0xffff0000u);
                        }
                    }
                }
            }
        }
        // 5-level within-half reduction; overlaps the gather waits
        float ssum = p;
#pragma unroll
        for (int off = 16; off; off >>= 1) ssum += __shfl_xor(ssum, off);
        float inv = __builtin_amdgcn_rcpf(ssum + p_self);

        if (act) {
            int f0 = 2 * lh;
            float bx = bg[((f0 & 3) << 4) | (f0 >> 2)];        // pi^-1(f0)
            float by = bg[(((f0 + 1) & 3) << 4) | (f0 >> 2)];  // pi^-1(f0+1)
            float ox = (ax0 + ax1 + p_self * __uint_as_float(hvs << 16)) * inv + bx;
            float oy = (ay0 + ay1 + p_self * __uint_as_float(hvs & 0xffff0000u)) * inv + by;
            unsigned int pck = (unsigned int)f2bf(ox) | ((unsigned int)f2bf(oy) << 16);
            *(unsigned int*)(out + (size_t)node * ldo + f0) = pck;
        }
        return;
    }

    // rare fallback: whole wave handles each node sequentially (proven path)
    float bgv = bg[((lane & 3) << 4) | (lane >> 2)];
    if (nodeA < N)
        gat_node_fullwave(nodeA, csr_ptr, csr_src, h, as_, ad_, bgv, out, ldo, lane);
    if (nodeA + 1 < N)
        gat_node_fullwave(nodeA + 1, csr_ptr, csr_src, h, as_, ad_, bgv, out, ldo, lane);
}

extern "C" void kernel_launch(void* const* d_in, const int* in_sizes, int n_in,
                              void* d_out, int out_size, void* d_ws, size_t ws_size,
                              hipStream_t stream) {
    const float* x = (const float*)d_in[0];
    const int* edges = (const int*)d_in[1];
    const float* Wg = (const float*)d_in[2];
    const float* a_src = (const float*)d_in[3];
    const float* a_dst = (const float*)d_in[4];
    const float* bg = (const float*)d_in[5];
    const float* W1 = (const float*)d_in[6];
    const float* b1 = (const float*)d_in[7];
    const float* W2 = (const float*)d_in[8];
    const float* b2 = (const float*)d_in[9];
    float* out = (float*)d_out;

    const int N = in_sizes[0] / DD;          // 100000
    const int E = in_sizes[1] / (2 * RREL);  // 1000000
    const int NB = (N + BSZ - 1) >> BSH;     // 98 buckets (requires N <= 131072)

    // workspace layout (256B aligned)
    size_t off = 0;
    auto alloc = [&](size_t bytes) {
        size_t o = off;
        off = (off + bytes + 255) & ~(size_t)255;
        return o;
    };
    char* ws = (char*)d_ws;
    unsigned short* combined = (unsigned short*)(ws + alloc((size_t)N * 320 * 2));  // bf16
    unsigned short* h4 = (unsigned short*)(ws + alloc((size_t)4 * N * 64 * 2));
    float* wsrc = (float*)(ws + alloc(LLAY * RREL * DD * 4));
    float* wdst = (float*)(ws + alloc(LLAY * RREL * DD * 4));
    unsigned short* WgT = (unsigned short*)(ws + alloc(8 * 4096 * 2));
    unsigned short* W1T = (unsigned short*)(ws + alloc(2 * 64 * 320 * 2));
    unsigned short* W2T = (unsigned short*)(ws + alloc(2 * 4096 * 2));
    int* btot = (int*)(ws + alloc((size_t)RREL * NB * 4));
    int* bucketoff = (int*)(ws + alloc((size_t)RREL * (NB + 1) * 4));
    int* bpos = (int*)(ws + alloc((size_t)RREL * NB * 4));
    unsigned int* packed = (unsigned int*)(ws + alloc((size_t)RREL * E * 4));  // also as4/ad4
    int* csr_ptr = (int*)(ws + alloc((size_t)RREL * (N + 1) * 4));
    int* csr_src = (int*)(ws + alloc((size_t)RREL * E * 4));
    (void)ws_size;
    float* as4 = (float*)packed;  // packed dead after CSR build
    float* ad4 = as4 + (size_t)4 * N;

    const int ebblocks = (E + EPB - 1) / EPB;

    // --- preprocessing ---
    k_zero<<<dim3((RREL * NB + 255) / 256), dim3(256), 0, stream>>>(btot, RREL * NB);
    k_wvec<<<dim3(2), dim3(256), 0, stream>>>(Wg, a_src, a_dst, wsrc, wdst);
    k_prep<<<dim3(320), dim3(256), 0, stream>>>(Wg, W1, W2, WgT, W1T, W2T);
    k_copy_x<<<dim3((N * 32 + 255) / 256), dim3(256), 0, stream>>>(x, combined, N);
    k_bhist<<<dim3(ebblocks, RREL), dim3(256), 0, stream>>>(edges, btot, E, NB);
    k_bscan<<<dim3(1), dim3(64), 0, stream>>>(btot, bucketoff, bpos, csr_ptr, N, E, NB);
    k_binscatter<<<dim3(ebblocks, RREL), dim3(256), 0, stream>>>(edges, bpos, packed, E, NB);
    k_bucket_sort<<<dim3(NB, RREL), dim3(256), 0, stream>>>(packed, bucketoff, csr_ptr, csr_src,
                                                            N, E, NB);

    const int gemm_blocks = (N + 255) / 256;
    // k_gat: 8 nodes/block (2 nodes/wave); grid = 8 * ceil(bpr/2) so lb%8
    // encodes {relation pair -> XCD} and covers all (r, idx) pairs.
    const int bpr = (N + 7) / 8;
    const int gat_grid = 8 * ((bpr + 1) / 2);

    for (int l = 0; l < LLAY; l++) {
        k_hgemm<<<dim3(gemm_blocks), dim3(256), 0, stream>>>(
            combined, WgT + (size_t)l * 4 * 4096, wsrc + l * 256, wdst + l * 256, h4, as4, ad4, N);
        k_gat<<<dim3(gat_grid), dim3(256), 0, stream>>>(
            csr_ptr, csr_src, h4, as4, ad4, bg + (size_t)l * RREL * DD,
            combined + 64, 320, N, E);
        if (l == LLAY - 1) {
            k_mlp<false><<<dim3(gemm_blocks), dim3(256), 0, stream>>>(
                combined, W1T + (size_t)l * 20480, b1 + l * DD, W2T + (size_t)l * 4096,
                b2 + l * DD, nullptr, out, DD, N);
        } else {
            k_mlp<true><<<dim3(gemm_blocks), dim3(256), 0, stream>>>(
                combined, W1T + (size_t)l * 20480, b1 + l * DD, W2T + (size_t)l * 4096,
                b2 + l * DD, combined, nullptr, 320, N);
        }
    }
}

// Round 7
// 466.403 us; speedup vs baseline: 1.4267x; 1.0813x over previous
//
#include <hip/hip_runtime.h>
#include <hip/hip_bf16.h>
#include <math.h>

// Problem constants (from reference): D=64, L=2, R=4. N, E derived from sizes.
#define DD 64
#define RREL 4
#define LLAY 2
#define NEG_SLOPE 0.2f
#define EPB 4096   // edges per block in binning passes
#define BSH 10     // bucket shift: 1024 nodes per bucket
#define BSZ 1024

typedef __attribute__((ext_vector_type(8))) short short8;
typedef __attribute__((ext_vector_type(4))) short short4v;
typedef __attribute__((ext_vector_type(4))) float float4v;

__device__ __forceinline__ float lrelu(float x) { return x > 0.f ? x : NEG_SLOPE * x; }

// fp32 -> bf16 round-to-nearest-even (finite values)
__device__ __forceinline__ unsigned short f2bf(float f) {
    unsigned int u = __float_as_uint(f);
    return (unsigned short)((u + 0x7FFFu + ((u >> 16) & 1u)) >> 16);
}
__device__ __forceinline__ float bf2f(unsigned short u) {
    return __uint_as_float((unsigned int)u << 16);
}
__device__ __forceinline__ float bflo(unsigned int u) { return __uint_as_float(u << 16); }
__device__ __forceinline__ float bfhi(unsigned int u) {
    return __uint_as_float(u & 0xffff0000u);
}

// ---------- small precompute: wsrc/wdst = Wg @ a_src, Wg @ a_dst ----------
__global__ void k_wvec(const float* __restrict__ Wg, const float* __restrict__ asrc,
                       const float* __restrict__ adst, float* __restrict__ wsrc,
                       float* __restrict__ wdst) {
    int idx = blockIdx.x * blockDim.x + threadIdx.x;  // L*R*64 = 512
    if (idx >= LLAY * RREL * DD) return;
    int k = idx & 63;
    int lr = idx >> 6;
    const float* W = Wg + (size_t)lr * DD * DD;
    const float* as = asrc + lr * DD;
    const float* ad = adst + lr * DD;
    float s1 = 0.f, s2 = 0.f;
#pragma unroll
    for (int j = 0; j < DD; j++) {
        float w = W[k * DD + j];
        s1 += w * as[j];
        s2 += w * ad[j];
    }
    wsrc[idx] = s1;
    wdst[idx] = s2;
}

// ---------- weight prep: bf16, transposed [n][k]; W1 k-rows pi-permuted ----------
// pi(n) = (n&15)*4 + (n>>4)  (h-gemm packed-store column permutation)
// pi^-1(f) = (f&3)*16 + (f>>2)
__global__ void k_prep(const float* __restrict__ Wg, const float* __restrict__ W1,
                       const float* __restrict__ W2, unsigned short* __restrict__ WgT,
                       unsigned short* __restrict__ W1T, unsigned short* __restrict__ W2T) {
    int idx = blockIdx.x * blockDim.x + threadIdx.x;
    if (idx < 8 * 4096) {  // WgT[lr][n][k] = Wg[lr][k][n]
        int lr = idx >> 12, rem = idx & 4095, n = rem >> 6, k = rem & 63;
        WgT[idx] = f2bf(Wg[(size_t)lr * 4096 + k * 64 + n]);
    } else if (idx < 32768 + 2 * 64 * 320) {  // W1T[l][n][kk]
        int i = idx - 32768;
        int l = i / 20480, rem = i % 20480, n = rem / 320, kk = rem % 320;
        int src;
        if (kk < 64) src = kk;  // x-slice: unpermuted
        else {
            int r = (kk - 64) >> 6, f = (kk - 64) & 63;
            src = 64 + r * 64 + ((f & 3) * 16) + (f >> 2);  // h-slices: pi^-1
        }
        W1T[i] = f2bf(W1[(size_t)l * 20480 + src * 64 + n]);
    } else if (idx < 32768 + 40960 + 2 * 4096) {  // W2T[l][n][k] = W2[l][k][n]
        int i = idx - 73728;
        int l = i >> 12, rem = i & 4095, n = rem >> 6, k = rem & 63;
        W2T[i] = f2bf(W2[(size_t)l * 4096 + k * 64 + n]);
    }
}

// ---------- copy x into combined[:,0:64] (bf16, stride 320) ----------
__global__ void k_copy_x(const float* __restrict__ x, unsigned short* __restrict__ combined,
                         int N) {
    int i = blockIdx.x * blockDim.x + threadIdx.x;  // N*32 uints
    if (i >= N * 32) return;
    int row = i >> 5, c2 = i & 31;
    float2 v = *(const float2*)(x + (size_t)row * DD + c2 * 2);
    unsigned int p = (unsigned int)f2bf(v.x) | ((unsigned int)f2bf(v.y) << 16);
    *(unsigned int*)(combined + (size_t)row * 320 + c2 * 2) = p;
}

// ---------- zero int buffer ----------
__global__ void k_zero(int* __restrict__ p, int n) {
    int i = blockIdx.x * blockDim.x + threadIdx.x;
    if (i < n) p[i] = 0;
}

// ---------- CSR pass A0: coarse bucket histogram (LDS-privatized) ----------
__global__ __launch_bounds__(256) void k_bhist(const int* __restrict__ edges,
                                               int* __restrict__ btot, int E, int NB) {
    int r = blockIdx.y;
    int e0 = blockIdx.x * EPB;
    int t = threadIdx.x;
    __shared__ int lh[128];
    for (int i = t; i < 128; i += 256) lh[i] = 0;
    __syncthreads();
    const int* dstp = edges + (size_t)r * 2 * E + E;
#pragma unroll
    for (int i = 0; i < EPB / 256; i++) {
        int e = e0 + t + 256 * i;
        if (e < E) atomicAdd(&lh[dstp[e] >> BSH], 1);
    }
    __syncthreads();
    for (int i = t; i < NB; i += 256) {
        int c = lh[i];
        if (c) atomicAdd(&btot[r * NB + i], c);
    }
}

// ---------- CSR pass A1: serial scan of bucket totals (tiny) ----------
__global__ void k_bscan(const int* __restrict__ btot, int* __restrict__ bucketoff,
                        int* __restrict__ bpos, int* __restrict__ csr_ptr, int N, int E, int NB) {
    int r = threadIdx.x;
    if (r >= RREL) return;
    int run = 0;
    for (int b = 0; b < NB; b++) {
        bucketoff[r * (NB + 1) + b] = run;
        bpos[r * NB + b] = run;
        run += btot[r * NB + b];
    }
    bucketoff[r * (NB + 1) + NB] = run;  // == E
    csr_ptr[(size_t)r * (N + 1) + N] = E;
}

// ---------- CSR pass A2: block-aggregated bin scatter (dense writes) ----------
__global__ __launch_bounds__(256) void k_binscatter(const int* __restrict__ edges,
                                                    int* __restrict__ bpos,
                                                    unsigned int* __restrict__ packed, int E,
                                                    int NB) {
    int r = blockIdx.y;
    int e0 = blockIdx.x * EPB;
    int t = threadIdx.x;
    __shared__ int lh[128], lbase[128];
    for (int i = t; i < 128; i += 256) lh[i] = 0;
    __syncthreads();
    const int* srcp = edges + (size_t)r * 2 * E;
    const int* dstp = srcp + E;
    int md[EPB / 256], ms[EPB / 256];
#pragma unroll
    for (int i = 0; i < EPB / 256; i++) {
        int e = e0 + t + 256 * i;
        int d = -1, s = 0;
        if (e < E) {
            d = dstp[e];
            s = srcp[e];
            atomicAdd(&lh[d >> BSH], 1);
        }
        md[i] = d;
        ms[i] = s;
    }
    __syncthreads();
    for (int i = t; i < NB; i += 256) {
        int c = lh[i];
        lbase[i] = c ? atomicAdd(&bpos[r * NB + i], c) : 0;
        lh[i] = 0;
    }
    __syncthreads();
#pragma unroll
    for (int i = 0; i < EPB / 256; i++) {
        if (md[i] >= 0) {
            int b = md[i] >> BSH;
            int p = lbase[b] + atomicAdd(&lh[b], 1);
            packed[(size_t)r * E + p] =
                ((unsigned int)(md[i] & (BSZ - 1)) << 17) | (unsigned int)ms[i];
        }
    }
}

// ---------- CSR pass B: per-bucket counting sort (L2-local) + csr_ptr ----------
__global__ __launch_bounds__(256) void k_bucket_sort(const unsigned int* __restrict__ packed,
                                                     const int* __restrict__ bucketoff,
                                                     int* __restrict__ csr_ptr,
                                                     int* __restrict__ csr_src, int N, int E,
                                                     int NB) {
    int r = blockIdx.y, b = blockIdx.x;
    int t = threadIdx.x;
    __shared__ int pos[BSZ];
    __shared__ int tsum[256];
    int base = bucketoff[r * (NB + 1) + b];
    int cnt = bucketoff[r * (NB + 1) + b + 1] - base;
    const unsigned int* pk = packed + (size_t)r * E + base;
    for (int i = t; i < BSZ; i += 256) pos[i] = 0;
    __syncthreads();
    for (int i = t; i < cnt; i += 256) atomicAdd(&pos[pk[i] >> 17], 1);
    __syncthreads();
    int v[4];
    int s = 0;
#pragma unroll
    for (int i = 0; i < 4; i++) {
        v[i] = pos[t * 4 + i];
        s += v[i];
    }
    tsum[t] = s;
    __syncthreads();
    for (int off = 1; off < 256; off <<= 1) {
        int add = (t >= off) ? tsum[t - off] : 0;
        __syncthreads();
        tsum[t] += add;
        __syncthreads();
    }
    int run = tsum[t] - s;  // exclusive
    __syncthreads();
#pragma unroll
    for (int i = 0; i < 4; i++) {
        int node_l = t * 4 + i;
        pos[node_l] = run;
        int node = b * BSZ + node_l;
        if (node < N) csr_ptr[(size_t)r * (N + 1) + node] = base + run;
        run += v[i];
    }
    __syncthreads();
    for (int i = t; i < cnt; i += 256) {
        unsigned int p = pk[i];
        int d = p >> 17;
        int sidx = p & 0x1FFFF;
        int loc = atomicAdd(&pos[d], 1);
        csr_src[(size_t)r * E + base + loc] = sidx;
    }
}

// ======== MFMA GEMM kernels: M-tile 256 (4 waves x 64 rows), N=64, 16x16x32 bf16 ========

// ---------- fused h-gemm: h_r = X@Wg_r (bf16, pi-packed), as/ad = X@wvec ----------
__global__ __launch_bounds__(256, 3) void k_hgemm(const unsigned short* __restrict__ X,
                                                  const unsigned short* __restrict__ WgTl,
                                                  const float* __restrict__ wsrcl,
                                                  const float* __restrict__ wdstl,
                                                  unsigned short* __restrict__ h4,
                                                  float* __restrict__ as4,
                                                  float* __restrict__ ad4, int N) {
    __shared__ __align__(16) unsigned short Xb[256][72];
    __shared__ __align__(16) unsigned short Wb[64][72];
    __shared__ float wsS[4][64], wdS[4][64];
    int tid = threadIdx.x, wave = tid >> 6, lane = tid & 63;
    int l15 = lane & 15, q = lane >> 4;
    int row0 = blockIdx.x * 256;
#pragma unroll
    for (int i = 0; i < 8; i++) {
        int f = tid + 256 * i;
        int rr = f >> 3, seg = f & 7;
        int grow = row0 + rr;
        short8 v = (short8){0, 0, 0, 0, 0, 0, 0, 0};
        if (grow < N) v = *(const short8*)(X + (size_t)grow * 320 + seg * 8);
        *(short8*)&Xb[rr][seg * 8] = v;
    }
    wsS[tid >> 6][tid & 63] = wsrcl[tid];
    wdS[tid >> 6][tid & 63] = wdstl[tid];
    __syncthreads();
    short8 afr[4][2];
#pragma unroll
    for (int mt = 0; mt < 4; mt++)
#pragma unroll
        for (int ks = 0; ks < 2; ks++)
            afr[mt][ks] = *(const short8*)&Xb[wave * 64 + mt * 16 + l15][ks * 32 + q * 8];
    {
        int grow = row0 + tid;
        float s[4] = {0.f, 0.f, 0.f, 0.f}, d[4] = {0.f, 0.f, 0.f, 0.f};
#pragma unroll
        for (int seg = 0; seg < 8; seg++) {
            short8 v = *(const short8*)&Xb[tid][seg * 8];
#pragma unroll
            for (int j = 0; j < 8; j++) {
                float xv = bf2f((unsigned short)v[j]);
                int k = seg * 8 + j;
#pragma unroll
                for (int r = 0; r < 4; r++) {
                    s[r] += xv * wsS[r][k];
                    d[r] += xv * wdS[r][k];
                }
            }
        }
        if (grow < N) {
#pragma unroll
            for (int r = 0; r < 4; r++) {
                as4[(size_t)r * N + grow] = s[r];
                ad4[(size_t)r * N + grow] = d[r];
            }
        }
    }
    for (int r = 0; r < 4; r++) {
        __syncthreads();
#pragma unroll
        for (int i = 0; i < 2; i++) {
            int f = tid + 256 * i;
            int n = f >> 3, seg = f & 7;
            *(short8*)&Wb[n][seg * 8] = *(const short8*)(WgTl + r * 4096 + n * 64 + seg * 8);
        }
        __syncthreads();
        short8 bfr[4][2];
#pragma unroll
        for (int nt = 0; nt < 4; nt++)
#pragma unroll
            for (int ks = 0; ks < 2; ks++)
                bfr[nt][ks] = *(const short8*)&Wb[nt * 16 + l15][ks * 32 + q * 8];
        float4v acc[4][4];
#pragma unroll
        for (int mt = 0; mt < 4; mt++)
#pragma unroll
            for (int nt = 0; nt < 4; nt++) acc[mt][nt] = (float4v){0.f, 0.f, 0.f, 0.f};
#pragma unroll
        for (int mt = 0; mt < 4; mt++)
#pragma unroll
            for (int nt = 0; nt < 4; nt++) {
                acc[mt][nt] = __builtin_amdgcn_mfma_f32_16x16x32_bf16(afr[mt][0], bfr[nt][0],
                                                                     acc[mt][nt], 0, 0, 0);
                acc[mt][nt] = __builtin_amdgcn_mfma_f32_16x16x32_bf16(afr[mt][1], bfr[nt][1],
                                                                     acc[mt][nt], 0, 0, 0);
            }
        unsigned short* hr = h4 + (size_t)r * N * 64;
#pragma unroll
        for (int mt = 0; mt < 4; mt++) {
            int rowb = row0 + wave * 64 + mt * 16 + q * 4;
#pragma unroll
            for (int reg = 0; reg < 4; reg++) {
                int row = rowb + reg;
                if (row < N) {
                    short4v sv;
                    sv[0] = (short)f2bf(acc[mt][0][reg]);
                    sv[1] = (short)f2bf(acc[mt][1][reg]);
                    sv[2] = (short)f2bf(acc[mt][2][reg]);
                    sv[3] = (short)f2bf(acc[mt][3][reg]);
                    *(short4v*)&hr[(size_t)row * 64 + l15 * 4] = sv;
                }
            }
        }
    }
}

// ---------- fused MLP: Y = (tanh(X[N,320]@W1+b1))@W2 + b2; bf16 or fp32 out ----------
template <bool BFOUT>
__global__ __launch_bounds__(256, 3) void k_mlp(const unsigned short* __restrict__ X,
                                                const unsigned short* __restrict__ W1Tl,
                                                const float* __restrict__ b1,
                                                const unsigned short* __restrict__ W2Tl,
                                                const float* __restrict__ b2,
                                                unsigned short* __restrict__ Ybf,
                                                float* __restrict__ Yf, int ldy, int N) {
    __shared__ __align__(16) unsigned short Xb[256][72];
    __shared__ __align__(16) unsigned short Wb[64][72];
    int tid = threadIdx.x, wave = tid >> 6, lane = tid & 63;
    int l15 = lane & 15, q = lane >> 4;
    int row0 = blockIdx.x * 256;
    float4v acc[4][4];
#pragma unroll
    for (int mt = 0; mt < 4; mt++)
#pragma unroll
        for (int nt = 0; nt < 4; nt++) acc[mt][nt] = (float4v){0.f, 0.f, 0.f, 0.f};
    for (int kc = 0; kc < 320; kc += 64) {
        __syncthreads();
#pragma unroll
        for (int i = 0; i < 8; i++) {
            int f = tid + 256 * i;
            int rr = f >> 3, seg = f & 7;
            int grow = row0 + rr;
            short8 v = (short8){0, 0, 0, 0, 0, 0, 0, 0};
            if (grow < N) v = *(const short8*)(X + (size_t)grow * 320 + kc + seg * 8);
            *(short8*)&Xb[rr][seg * 8] = v;
        }
#pragma unroll
        for (int i = 0; i < 2; i++) {
            int f = tid + 256 * i;
            int n = f >> 3, seg = f & 7;
            *(short8*)&Wb[n][seg * 8] = *(const short8*)(W1Tl + n * 320 + kc + seg * 8);
        }
        __syncthreads();
        short8 bfr[4][2];
#pragma unroll
        for (int nt = 0; nt < 4; nt++)
#pragma unroll
            for (int ks = 0; ks < 2; ks++)
                bfr[nt][ks] = *(const short8*)&Wb[nt * 16 + l15][ks * 32 + q * 8];
#pragma unroll
        for (int mt = 0; mt < 4; mt++) {
            short8 a0 = *(const short8*)&Xb[wave * 64 + mt * 16 + l15][q * 8];
            short8 a1 = *(const short8*)&Xb[wave * 64 + mt * 16 + l15][32 + q * 8];
#pragma unroll
            for (int nt = 0; nt < 4; nt++) {
                acc[mt][nt] =
                    __builtin_amdgcn_mfma_f32_16x16x32_bf16(a0, bfr[nt][0], acc[mt][nt], 0, 0, 0);
                acc[mt][nt] =
                    __builtin_amdgcn_mfma_f32_16x16x32_bf16(a1, bfr[nt][1], acc[mt][nt], 0, 0, 0);
            }
        }
    }
    // tanh epilogue -> LDS (Xb reuse; covers all 256 rows x 64 cols exactly once)
    __syncthreads();
#pragma unroll
    for (int mt = 0; mt < 4; mt++) {
        int rlb = wave * 64 + mt * 16 + q * 4;
#pragma unroll
        for (int reg = 0; reg < 4; reg++) {
#pragma unroll
            for (int nt = 0; nt < 4; nt++) {
                int n = nt * 16 + l15;
                Xb[rlb + reg][n] = f2bf(tanhf(acc[mt][nt][reg] + b1[n]));
            }
        }
    }
    // stage W2 into Wb
#pragma unroll
    for (int i = 0; i < 2; i++) {
        int f = tid + 256 * i;
        int n = f >> 3, seg = f & 7;
        *(short8*)&Wb[n][seg * 8] = *(const short8*)(W2Tl + n * 64 + seg * 8);
    }
    __syncthreads();
    // w2 phase
    short8 bfr[4][2];
#pragma unroll
    for (int nt = 0; nt < 4; nt++)
#pragma unroll
        for (int ks = 0; ks < 2; ks++)
            bfr[nt][ks] = *(const short8*)&Wb[nt * 16 + l15][ks * 32 + q * 8];
    float4v acc2[4][4];
#pragma unroll
    for (int mt = 0; mt < 4; mt++)
#pragma unroll
        for (int nt = 0; nt < 4; nt++) acc2[mt][nt] = (float4v){0.f, 0.f, 0.f, 0.f};
#pragma unroll
    for (int mt = 0; mt < 4; mt++) {
        short8 a0 = *(const short8*)&Xb[wave * 64 + mt * 16 + l15][q * 8];
        short8 a1 = *(const short8*)&Xb[wave * 64 + mt * 16 + l15][32 + q * 8];
#pragma unroll
        for (int nt = 0; nt < 4; nt++) {
            acc2[mt][nt] =
                __builtin_amdgcn_mfma_f32_16x16x32_bf16(a0, bfr[nt][0], acc2[mt][nt], 0, 0, 0);
            acc2[mt][nt] =
                __builtin_amdgcn_mfma_f32_16x16x32_bf16(a1, bfr[nt][1], acc2[mt][nt], 0, 0, 0);
        }
    }
#pragma unroll
    for (int mt = 0; mt < 4; mt++) {
        int rowb = row0 + wave * 64 + mt * 16 + q * 4;
#pragma unroll
        for (int reg = 0; reg < 4; reg++) {
            int row = rowb + reg;
            if (row < N) {
#pragma unroll
                for (int nt = 0; nt < 4; nt++) {
                    int n = nt * 16 + l15;
                    float v = acc2[mt][nt][reg] + b2[n];
                    if (BFOUT)
                        Ybf[(size_t)row * ldy + n] = f2bf(v);
                    else
                        Yf[(size_t)row * ldy + n] = v;
                }
            }
        }
    }
}

// ---------- full-wave per-node GAT (rare fallback; gathers as_ directly) ----------
__device__ void gat_node_fullwave(int node, const int* __restrict__ csr_ptr,
                                  const int* __restrict__ csr_src,
                                  const unsigned short* __restrict__ h,
                                  const float* __restrict__ as_,
                                  const float* __restrict__ ad_, float bgv,
                                  unsigned short* __restrict__ out, int ldo, int lane) {
    float adv = ad_[node];
    float e_self = lrelu(as_[node] + adv);
    int beg = csr_ptr[node], end = csr_ptr[node + 1];
    int cnt = end - beg;

    if (cnt <= 64) {
        int s = 0;
        float e_lane = -3.0e38f;
        if (lane < cnt) {
            s = csr_src[beg + lane];
            e_lane = lrelu(as_[s] + adv);
        }
        float m = fmaxf(e_lane, e_self);
#pragma unroll
        for (int off = 32; off; off >>= 1) m = fmaxf(m, __shfl_xor(m, off));
        float p = (lane < cnt) ? expf(e_lane - m) : 0.f;
        float ssum = p;
#pragma unroll
        for (int off = 32; off; off >>= 1) ssum += __shfl_xor(ssum, off);
        float p_self = expf(e_self - m);
        float inv = 1.f / (ssum + p_self);
        float alpha = p * inv;
        float acc = p_self * inv * bf2f(h[(size_t)node * DD + lane]);
        for (int j0 = 0; j0 < cnt; ++j0) {
            int ss = __shfl(s, j0);
            float aa = __shfl(alpha, j0);
            acc += aa * bf2f(h[(size_t)ss * DD + lane]);
        }
        out[(size_t)node * ldo + lane] = f2bf(acc + bgv);
        return;
    }

    float m = e_self;
    for (int j = beg + lane; j < end; j += 64) m = fmaxf(m, lrelu(as_[csr_src[j]] + adv));
#pragma unroll
    for (int off = 32; off; off >>= 1) m = fmaxf(m, __shfl_xor(m, off));
    float ssum = 0.f;
    for (int j = beg + lane; j < end; j += 64) ssum += expf(lrelu(as_[csr_src[j]] + adv) - m);
#pragma unroll
    for (int off = 32; off; off >>= 1) ssum += __shfl_xor(ssum, off);
    ssum += expf(e_self - m);
    float inv = 1.f / ssum;
    float acc = expf(e_self - m) * inv * bf2f(h[(size_t)node * DD + lane]);
    for (int j0 = beg; j0 < end; j0 += 64) {
        int j = j0 + lane;
        int s = 0;
        float alpha = 0.f;
        if (j < end) {
            s = csr_src[j];
            alpha = expf(lrelu(as_[s] + adv) - m) * inv;
        }
        int c = end - j0;
        if (c > 64) c = 64;
        for (int t = 0; t < c; ++t) {
            int ss = __shfl(s, t);
            float aa = __shfl(alpha, t);
            acc += aa * bf2f(h[(size_t)ss * DD + lane]);
        }
    }
    out[(size_t)node * ldo + lane] = f2bf(acc + bgv);
}

// ---------- GAT: 4 nodes/wave (quarter = node, 16 lanes, 4 feat/lane) ----------
// Changes vs R6 (theory: remaining cost = per-wave fixed chain + gather issue):
//  * 4 nodes/wave: wave count halves again; fixed chain amortized over 4 nodes;
//    slots/node ~ E[max of 4 Poisson(10)]/4 ~ 3.5 vs 5.9 at 2 nodes/wave.
//  * 8B uint2 gathers (4 bf16 feat/lane x 16 lanes = full 128B row per node
//    per slot): VMEM instructions per edge halved, same coalescing/traffic.
//  * degree 17..32: second staging round under a wave-uniform guard (~10% of
//    waves); vmax>32 -> proven full-wave fallback (P ~ 1e-8).
//  * quarters fully independent: own 4-level reduction (offsets 8,4,2,1),
//    own uint2 store. bias: pi^-1(4lq+i) = i*16+lq -> bg[i*16+lq].
__global__ __launch_bounds__(256) void k_gat(const int* __restrict__ csr_ptr4,
                                             const int* __restrict__ csr_src4,
                                             const unsigned short* __restrict__ h4,
                                             const float* __restrict__ as4,
                                             const float* __restrict__ ad4,
                                             const float* __restrict__ bg4,
                                             unsigned short* __restrict__ outbase, int ldo,
                                             int N, int E) {
    __shared__ int lsa_s[4][4][32];
    __shared__ float lsa_p[4][4][32];
    int lb = blockIdx.x;
    int r = (lb & 7) >> 1;                     // relation -> XCD pair
    int idx = ((lb >> 3) << 1) + (lb & 1);     // block index within relation
    int wave = threadIdx.x >> 6, lane = threadIdx.x & 63;
    int qd = lane >> 4, lq = lane & 15;        // quarter (=node), lane-in-quarter
    int nodeA = idx * 16 + wave * 4;           // 16 nodes per block
    if (nodeA >= N) return;
    int node = nodeA + qd;
    bool act = node < N;

    const int* csr_ptr = csr_ptr4 + (size_t)r * (N + 1);
    const int* csr_src = csr_src4 + (size_t)r * E;
    const unsigned short* h = h4 + (size_t)r * N * 64;
    const float* as_ = as4 + (size_t)r * N;
    const float* ad_ = ad4 + (size_t)r * N;
    const float* bg = bg4 + (size_t)r * DD;
    unsigned short* out = outbase + (size_t)64 * r;

    int beg = 0, cnt = 0;
    if (act) {
        beg = csr_ptr[node];
        cnt = csr_ptr[node + 1] - beg;
    }
    int m2 = max(cnt, __shfl_xor(cnt, 16));
    int vmax = __builtin_amdgcn_readfirstlane(max(m2, __shfl_xor(m2, 32)));

    if (vmax <= 32) {
        // stage round 1: edges [0,16)
        bool in0 = lq < cnt;
        int s0 = 0;
        if (in0) s0 = csr_src[beg + lq];
        lsa_s[wave][qd][lq] = s0;
        // stage round 2 (wave-uniform, ~10% of waves): edges [16,32)
        bool need2 = vmax > 16;
        bool in1 = false;
        int s1 = 0;
        if (need2) {
            in1 = (lq + 16) < cnt;
            if (in1) s1 = csr_src[beg + lq + 16];
            lsa_s[wave][qd][lq + 16] = s1;
        }
        float adv = act ? ad_[node] : 0.f;
        float e_self = act ? lrelu(as_[node] + adv) : 0.f;
        float asl0 = in0 ? as_[s0] : 0.f;          // random 4B gather, L2-local
        float p0 = in0 ? __expf(lrelu(asl0 + adv)) : 0.f;
        lsa_p[wave][qd][lq] = p0;
        float p1 = 0.f;
        if (need2) {
            float asl1 = in1 ? as_[s1] : 0.f;
            p1 = in1 ? __expf(lrelu(asl1 + adv)) : 0.f;
            lsa_p[wave][qd][lq + 16] = p1;
        }
        float p_self = __expf(e_self);

        const char* hb = (const char*)h;
        unsigned lane8 = (unsigned)(lq << 3);
        uint2 hvs = make_uint2(0u, 0u);
        if (act) hvs = *(const uint2*)(hb + (((unsigned)node) << 7) + lane8);

        float a0 = 0.f, a1 = 0.f, a2 = 0.f, a3 = 0.f;
        float c0 = 0.f, c1 = 0.f, c2 = 0.f, c3 = 0.f;
        const int* sp = &lsa_s[wave][qd][0];
        const float* pp = &lsa_p[wave][qd][0];
        for (int j0 = 0; j0 < vmax; j0 += 8) {     // uniform scalar loop
#pragma unroll
            for (int g = 0; g < 2; g++) {
                if (j0 + g * 4 < vmax) {           // uniform quad guard
#pragma unroll
                    for (int u = 0; u < 4; u++) {
                        int sv = sp[j0 + g * 4 + u];       // ds_read_b32
                        unsigned voff = ((unsigned)sv << 7) + lane8;
                        uint2 hv = *(const uint2*)(hb + voff);  // 8B row chunk
                        float pw = pp[j0 + g * 4 + u];     // ds_read_b32
                        if (u & 1) {
                            c0 += pw * bflo(hv.x);
                            c1 += pw * bfhi(hv.x);
                            c2 += pw * bflo(hv.y);
                            c3 += pw * bfhi(hv.y);
                        } else {
                            a0 += pw * bflo(hv.x);
                            a1 += pw * bfhi(hv.x);
                            a2 += pw * bflo(hv.y);
                            a3 += pw * bfhi(hv.y);
                        }
                    }
                }
            }
        }
        // 4-level within-quarter reduction; overlaps the gather waits
        float ssum = p0 + p1;
#pragma unroll
        for (int off = 8; off; off >>= 1) ssum += __shfl_xor(ssum, off);
        float inv = __builtin_amdgcn_rcpf(ssum + p_self);

        if (act) {
            // features f = 4*lq + i; pi^-1(f) = i*16 + lq
            float o0 = (a0 + c0 + p_self * bflo(hvs.x)) * inv + bg[lq];
            float o1 = (a1 + c1 + p_self * bfhi(hvs.x)) * inv + bg[16 + lq];
            float o2 = (a2 + c2 + p_self * bflo(hvs.y)) * inv + bg[32 + lq];
            float o3 = (a3 + c3 + p_self * bfhi(hvs.y)) * inv + bg[48 + lq];
            uint2 pck;
            pck.x = (unsigned int)f2bf(o0) | ((unsigned int)f2bf(o1) << 16);
            pck.y = (unsigned int)f2bf(o2) | ((unsigned int)f2bf(o3) << 16);
            *(uint2*)(out + (size_t)node * ldo + 4 * lq) = pck;
        }
        return;
    }

    // rare fallback: whole wave handles each node sequentially (proven path)
    float bgv = bg[((lane & 3) << 4) | (lane >> 2)];
#pragma unroll
    for (int k = 0; k < 4; k++) {
        if (nodeA + k < N)
            gat_node_fullwave(nodeA + k, csr_ptr, csr_src, h, as_, ad_, bgv, out, ldo, lane);
    }
}

extern "C" void kernel_launch(void* const* d_in, const int* in_sizes, int n_in,
                              void* d_out, int out_size, void* d_ws, size_t ws_size,
                              hipStream_t stream) {
    const float* x = (const float*)d_in[0];
    const int* edges = (const int*)d_in[1];
    const float* Wg = (const float*)d_in[2];
    const float* a_src = (const float*)d_in[3];
    const float* a_dst = (const float*)d_in[4];
    const float* bg = (const float*)d_in[5];
    const float* W1 = (const float*)d_in[6];
    const float* b1 = (const float*)d_in[7];
    const float* W2 = (const float*)d_in[8];
    const float* b2 = (const float*)d_in[9];
    float* out = (float*)d_out;

    const int N = in_sizes[0] / DD;          // 100000
    const int E = in_sizes[1] / (2 * RREL);  // 1000000
    const int NB = (N + BSZ - 1) >> BSH;     // 98 buckets (requires N <= 131072)

    // workspace layout (256B aligned)
    size_t off = 0;
    auto alloc = [&](size_t bytes) {
        size_t o = off;
        off = (off + bytes + 255) & ~(size_t)255;
        return o;
    };
    char* ws = (char*)d_ws;
    unsigned short* combined = (unsigned short*)(ws + alloc((size_t)N * 320 * 2));  // bf16
    unsigned short* h4 = (unsigned short*)(ws + alloc((size_t)4 * N * 64 * 2));
    float* wsrc = (float*)(ws + alloc(LLAY * RREL * DD * 4));
    float* wdst = (float*)(ws + alloc(LLAY * RREL * DD * 4));
    unsigned short* WgT = (unsigned short*)(ws + alloc(8 * 4096 * 2));
    unsigned short* W1T = (unsigned short*)(ws + alloc(2 * 64 * 320 * 2));
    unsigned short* W2T = (unsigned short*)(ws + alloc(2 * 4096 * 2));
    int* btot = (int*)(ws + alloc((size_t)RREL * NB * 4));
    int* bucketoff = (int*)(ws + alloc((size_t)RREL * (NB + 1) * 4));
    int* bpos = (int*)(ws + alloc((size_t)RREL * NB * 4));
    unsigned int* packed = (unsigned int*)(ws + alloc((size_t)RREL * E * 4));  // also as4/ad4
    int* csr_ptr = (int*)(ws + alloc((size_t)RREL * (N + 1) * 4));
    int* csr_src = (int*)(ws + alloc((size_t)RREL * E * 4));
    (void)ws_size;
    float* as4 = (float*)packed;  // packed dead after CSR build
    float* ad4 = as4 + (size_t)4 * N;

    const int ebblocks = (E + EPB - 1) / EPB;

    // --- preprocessing ---
    k_zero<<<dim3((RREL * NB + 255) / 256), dim3(256), 0, stream>>>(btot, RREL * NB);
    k_wvec<<<dim3(2), dim3(256), 0, stream>>>(Wg, a_src, a_dst, wsrc, wdst);
    k_prep<<<dim3(320), dim3(256), 0, stream>>>(Wg, W1, W2, WgT, W1T, W2T);
    k_copy_x<<<dim3((N * 32 + 255) / 256), dim3(256), 0, stream>>>(x, combined, N);
    k_bhist<<<dim3(ebblocks, RREL), dim3(256), 0, stream>>>(edges, btot, E, NB);
    k_bscan<<<dim3(1), dim3(64), 0, stream>>>(btot, bucketoff, bpos, csr_ptr, N, E, NB);
    k_binscatter<<<dim3(ebblocks, RREL), dim3(256), 0, stream>>>(edges, bpos, packed, E, NB);
    k_bucket_sort<<<dim3(NB, RREL), dim3(256), 0, stream>>>(packed, bucketoff, csr_ptr, csr_src,
                                                            N, E, NB);

    const int gemm_blocks = (N + 255) / 256;
    // k_gat: 16 nodes/block (4 nodes/wave); grid = 8 * ceil(bpr/2) so lb%8
    // encodes {relation pair -> XCD} and covers all (r, idx) pairs.
    const int bpr = (N + 15) / 16;
    const int gat_grid = 8 * ((bpr + 1) / 2);

    for (int l = 0; l < LLAY; l++) {
        k_hgemm<<<dim3(gemm_blocks), dim3(256), 0, stream>>>(
            combined, WgT + (size_t)l * 4 * 4096, wsrc + l * 256, wdst + l * 256, h4, as4, ad4, N);
        k_gat<<<dim3(gat_grid), dim3(256), 0, stream>>>(
            csr_ptr, csr_src, h4, as4, ad4, bg + (size_t)l * RREL * DD,
            combined + 64, 320, N, E);
        if (l == LLAY - 1) {
            k_mlp<false><<<dim3(gemm_blocks), dim3(256), 0, stream>>>(
                combined, W1T + (size_t)l * 20480, b1 + l * DD, W2T + (size_t)l * 4096,
                b2 + l * DD, nullptr, out, DD, N);
        } else {
            k_mlp<true><<<dim3(gemm_blocks), dim3(256), 0, stream>>>(
                combined, W1T + (size_t)l * 20480, b1 + l * DD, W2T + (size_t)l * 4096,
                b2 + l * DD, combined, nullptr, 320, N);
        }
    }
}

// Round 8
// 454.575 us; speedup vs baseline: 1.4638x; 1.0260x over previous
//
#include <hip/hip_runtime.h>
#include <hip/hip_bf16.h>
#include <math.h>

// Problem constants (from reference): D=64, L=2, R=4. N, E derived from sizes.
#define DD 64
#define RREL 4
#define LLAY 2
#define NEG_SLOPE 0.2f
#define EPB 4096   // edges per block in binning passes
#define BSH 10     // bucket shift: 1024 nodes per bucket
#define BSZ 1024

typedef __attribute__((ext_vector_type(8))) short short8;
typedef __attribute__((ext_vector_type(4))) short short4v;
typedef __attribute__((ext_vector_type(4))) float float4v;

__device__ __forceinline__ float lrelu(float x) { return x > 0.f ? x : NEG_SLOPE * x; }

// fp32 -> bf16 round-to-nearest-even (finite values)
__device__ __forceinline__ unsigned short f2bf(float f) {
    unsigned int u = __float_as_uint(f);
    return (unsigned short)((u + 0x7FFFu + ((u >> 16) & 1u)) >> 16);
}
__device__ __forceinline__ float bf2f(unsigned short u) {
    return __uint_as_float((unsigned int)u << 16);
}
__device__ __forceinline__ float bflo(unsigned int u) { return __uint_as_float(u << 16); }
__device__ __forceinline__ float bfhi(unsigned int u) {
    return __uint_as_float(u & 0xffff0000u);
}

// ---------- small precompute: wsrc/wdst = Wg @ a_src, Wg @ a_dst ----------
__global__ void k_wvec(const float* __restrict__ Wg, const float* __restrict__ asrc,
                       const float* __restrict__ adst, float* __restrict__ wsrc,
                       float* __restrict__ wdst) {
    int idx = blockIdx.x * blockDim.x + threadIdx.x;  // L*R*64 = 512
    if (idx >= LLAY * RREL * DD) return;
    int k = idx & 63;
    int lr = idx >> 6;
    const float* W = Wg + (size_t)lr * DD * DD;
    const float* as = asrc + lr * DD;
    const float* ad = adst + lr * DD;
    float s1 = 0.f, s2 = 0.f;
#pragma unroll
    for (int j = 0; j < DD; j++) {
        float w = W[k * DD + j];
        s1 += w * as[j];
        s2 += w * ad[j];
    }
    wsrc[idx] = s1;
    wdst[idx] = s2;
}

// ---------- weight prep: bf16, transposed [n][k]; W1 k-rows pi-permuted ----------
// pi(n) = (n&15)*4 + (n>>4)  (h-gemm packed-store column permutation)
// pi^-1(f) = (f&3)*16 + (f>>2)
__global__ void k_prep(const float* __restrict__ Wg, const float* __restrict__ W1,
                       const float* __restrict__ W2, unsigned short* __restrict__ WgT,
                       unsigned short* __restrict__ W1T, unsigned short* __restrict__ W2T) {
    int idx = blockIdx.x * blockDim.x + threadIdx.x;
    if (idx < 8 * 4096) {  // WgT[lr][n][k] = Wg[lr][k][n]
        int lr = idx >> 12, rem = idx & 4095, n = rem >> 6, k = rem & 63;
        WgT[idx] = f2bf(Wg[(size_t)lr * 4096 + k * 64 + n]);
    } else if (idx < 32768 + 2 * 64 * 320) {  // W1T[l][n][kk]
        int i = idx - 32768;
        int l = i / 20480, rem = i % 20480, n = rem / 320, kk = rem % 320;
        int src;
        if (kk < 64) src = kk;  // x-slice: unpermuted
        else {
            int r = (kk - 64) >> 6, f = (kk - 64) & 63;
            src = 64 + r * 64 + ((f & 3) * 16) + (f >> 2);  // h-slices: pi^-1
        }
        W1T[i] = f2bf(W1[(size_t)l * 20480 + src * 64 + n]);
    } else if (idx < 32768 + 40960 + 2 * 4096) {  // W2T[l][n][k] = W2[l][k][n]
        int i = idx - 73728;
        int l = i >> 12, rem = i & 4095, n = rem >> 6, k = rem & 63;
        W2T[i] = f2bf(W2[(size_t)l * 4096 + k * 64 + n]);
    }
}

// ---------- copy x into combined[:,0:64] (bf16, stride 320) ----------
__global__ void k_copy_x(const float* __restrict__ x, unsigned short* __restrict__ combined,
                         int N) {
    int i = blockIdx.x * blockDim.x + threadIdx.x;  // N*32 uints
    if (i >= N * 32) return;
    int row = i >> 5, c2 = i & 31;
    float2 v = *(const float2*)(x + (size_t)row * DD + c2 * 2);
    unsigned int p = (unsigned int)f2bf(v.x) | ((unsigned int)f2bf(v.y) << 16);
    *(unsigned int*)(combined + (size_t)row * 320 + c2 * 2) = p;
}

// ---------- zero int buffer ----------
__global__ void k_zero(int* __restrict__ p, int n) {
    int i = blockIdx.x * blockDim.x + threadIdx.x;
    if (i < n) p[i] = 0;
}

// ---------- CSR pass A0: coarse bucket histogram (LDS-privatized) ----------
__global__ __launch_bounds__(256) void k_bhist(const int* __restrict__ edges,
                                               int* __restrict__ btot, int E, int NB) {
    int r = blockIdx.y;
    int e0 = blockIdx.x * EPB;
    int t = threadIdx.x;
    __shared__ int lh[128];
    for (int i = t; i < 128; i += 256) lh[i] = 0;
    __syncthreads();
    const int* dstp = edges + (size_t)r * 2 * E + E;
#pragma unroll
    for (int i = 0; i < EPB / 256; i++) {
        int e = e0 + t + 256 * i;
        if (e < E) atomicAdd(&lh[dstp[e] >> BSH], 1);
    }
    __syncthreads();
    for (int i = t; i < NB; i += 256) {
        int c = lh[i];
        if (c) atomicAdd(&btot[r * NB + i], c);
    }
}

// ---------- CSR pass A1: serial scan of bucket totals (tiny) ----------
__global__ void k_bscan(const int* __restrict__ btot, int* __restrict__ bucketoff,
                        int* __restrict__ bpos, int* __restrict__ csr_ptr, int N, int E, int NB) {
    int r = threadIdx.x;
    if (r >= RREL) return;
    int run = 0;
    for (int b = 0; b < NB; b++) {
        bucketoff[r * (NB + 1) + b] = run;
        bpos[r * NB + b] = run;
        run += btot[r * NB + b];
    }
    bucketoff[r * (NB + 1) + NB] = run;  // == E
    csr_ptr[(size_t)r * (N + 1) + N] = E;
}

// ---------- CSR pass A2: block-aggregated bin scatter (dense writes) ----------
__global__ __launch_bounds__(256) void k_binscatter(const int* __restrict__ edges,
                                                    int* __restrict__ bpos,
                                                    unsigned int* __restrict__ packed, int E,
                                                    int NB) {
    int r = blockIdx.y;
    int e0 = blockIdx.x * EPB;
    int t = threadIdx.x;
    __shared__ int lh[128], lbase[128];
    for (int i = t; i < 128; i += 256) lh[i] = 0;
    __syncthreads();
    const int* srcp = edges + (size_t)r * 2 * E;
    const int* dstp = srcp + E;
    int md[EPB / 256], ms[EPB / 256];
#pragma unroll
    for (int i = 0; i < EPB / 256; i++) {
        int e = e0 + t + 256 * i;
        int d = -1, s = 0;
        if (e < E) {
            d = dstp[e];
            s = srcp[e];
            atomicAdd(&lh[d >> BSH], 1);
        }
        md[i] = d;
        ms[i] = s;
    }
    __syncthreads();
    for (int i = t; i < NB; i += 256) {
        int c = lh[i];
        lbase[i] = c ? atomicAdd(&bpos[r * NB + i], c) : 0;
        lh[i] = 0;
    }
    __syncthreads();
#pragma unroll
    for (int i = 0; i < EPB / 256; i++) {
        if (md[i] >= 0) {
            int b = md[i] >> BSH;
            int p = lbase[b] + atomicAdd(&lh[b], 1);
            packed[(size_t)r * E + p] =
                ((unsigned int)(md[i] & (BSZ - 1)) << 17) | (unsigned int)ms[i];
        }
    }
}

// ---------- CSR pass B: per-bucket counting sort (L2-local) + csr_ptr ----------
__global__ __launch_bounds__(256) void k_bucket_sort(const unsigned int* __restrict__ packed,
                                                     const int* __restrict__ bucketoff,
                                                     int* __restrict__ csr_ptr,
                                                     int* __restrict__ csr_src, int N, int E,
                                                     int NB) {
    int r = blockIdx.y, b = blockIdx.x;
    int t = threadIdx.x;
    __shared__ int pos[BSZ];
    __shared__ int tsum[256];
    int base = bucketoff[r * (NB + 1) + b];
    int cnt = bucketoff[r * (NB + 1) + b + 1] - base;
    const unsigned int* pk = packed + (size_t)r * E + base;
    for (int i = t; i < BSZ; i += 256) pos[i] = 0;
    __syncthreads();
    for (int i = t; i < cnt; i += 256) atomicAdd(&pos[pk[i] >> 17], 1);
    __syncthreads();
    int v[4];
    int s = 0;
#pragma unroll
    for (int i = 0; i < 4; i++) {
        v[i] = pos[t * 4 + i];
        s += v[i];
    }
    tsum[t] = s;
    __syncthreads();
    for (int off = 1; off < 256; off <<= 1) {
        int add = (t >= off) ? tsum[t - off] : 0;
        __syncthreads();
        tsum[t] += add;
        __syncthreads();
    }
    int run = tsum[t] - s;  // exclusive
    __syncthreads();
#pragma unroll
    for (int i = 0; i < 4; i++) {
        int node_l = t * 4 + i;
        pos[node_l] = run;
        int node = b * BSZ + node_l;
        if (node < N) csr_ptr[(size_t)r * (N + 1) + node] = base + run;
        run += v[i];
    }
    __syncthreads();
    for (int i = t; i < cnt; i += 256) {
        unsigned int p = pk[i];
        int d = p >> 17;
        int sidx = p & 0x1FFFF;
        int loc = atomicAdd(&pos[d], 1);
        csr_src[(size_t)r * E + base + loc] = sidx;
    }
}

// ======== MFMA GEMM kernels: M-tile 256 (4 waves x 64 rows), N=64, 16x16x32 bf16 ========

// ---------- fused h-gemm: h_r = X@Wg_r (bf16, pi-packed), as/ad = X@wvec ----------
__global__ __launch_bounds__(256, 3) void k_hgemm(const unsigned short* __restrict__ X,
                                                  const unsigned short* __restrict__ WgTl,
                                                  const float* __restrict__ wsrcl,
                                                  const float* __restrict__ wdstl,
                                                  unsigned short* __restrict__ h4,
                                                  float* __restrict__ as4,
                                                  float* __restrict__ ad4, int N) {
    __shared__ __align__(16) unsigned short Xb[256][72];
    __shared__ __align__(16) unsigned short Wb[64][72];
    __shared__ float wsS[4][64], wdS[4][64];
    int tid = threadIdx.x, wave = tid >> 6, lane = tid & 63;
    int l15 = lane & 15, q = lane >> 4;
    int row0 = blockIdx.x * 256;
#pragma unroll
    for (int i = 0; i < 8; i++) {
        int f = tid + 256 * i;
        int rr = f >> 3, seg = f & 7;
        int grow = row0 + rr;
        short8 v = (short8){0, 0, 0, 0, 0, 0, 0, 0};
        if (grow < N) v = *(const short8*)(X + (size_t)grow * 320 + seg * 8);
        *(short8*)&Xb[rr][seg * 8] = v;
    }
    wsS[tid >> 6][tid & 63] = wsrcl[tid];
    wdS[tid >> 6][tid & 63] = wdstl[tid];
    __syncthreads();
    short8 afr[4][2];
#pragma unroll
    for (int mt = 0; mt < 4; mt++)
#pragma unroll
        for (int ks = 0; ks < 2; ks++)
            afr[mt][ks] = *(const short8*)&Xb[wave * 64 + mt * 16 + l15][ks * 32 + q * 8];
    {
        int grow = row0 + tid;
        float s[4] = {0.f, 0.f, 0.f, 0.f}, d[4] = {0.f, 0.f, 0.f, 0.f};
#pragma unroll
        for (int seg = 0; seg < 8; seg++) {
            short8 v = *(const short8*)&Xb[tid][seg * 8];
#pragma unroll
            for (int j = 0; j < 8; j++) {
                float xv = bf2f((unsigned short)v[j]);
                int k = seg * 8 + j;
#pragma unroll
                for (int r = 0; r < 4; r++) {
                    s[r] += xv * wsS[r][k];
                    d[r] += xv * wdS[r][k];
                }
            }
        }
        if (grow < N) {
#pragma unroll
            for (int r = 0; r < 4; r++) {
                as4[(size_t)r * N + grow] = s[r];
                ad4[(size_t)r * N + grow] = d[r];
            }
        }
    }
    for (int r = 0; r < 4; r++) {
        __syncthreads();
#pragma unroll
        for (int i = 0; i < 2; i++) {
            int f = tid + 256 * i;
            int n = f >> 3, seg = f & 7;
            *(short8*)&Wb[n][seg * 8] = *(const short8*)(WgTl + r * 4096 + n * 64 + seg * 8);
        }
        __syncthreads();
        short8 bfr[4][2];
#pragma unroll
        for (int nt = 0; nt < 4; nt++)
#pragma unroll
            for (int ks = 0; ks < 2; ks++)
                bfr[nt][ks] = *(const short8*)&Wb[nt * 16 + l15][ks * 32 + q * 8];
        float4v acc[4][4];
#pragma unroll
        for (int mt = 0; mt < 4; mt++)
#pragma unroll
            for (int nt = 0; nt < 4; nt++) acc[mt][nt] = (float4v){0.f, 0.f, 0.f, 0.f};
#pragma unroll
        for (int mt = 0; mt < 4; mt++)
#pragma unroll
            for (int nt = 0; nt < 4; nt++) {
                acc[mt][nt] = __builtin_amdgcn_mfma_f32_16x16x32_bf16(afr[mt][0], bfr[nt][0],
                                                                     acc[mt][nt], 0, 0, 0);
                acc[mt][nt] = __builtin_amdgcn_mfma_f32_16x16x32_bf16(afr[mt][1], bfr[nt][1],
                                                                     acc[mt][nt], 0, 0, 0);
            }
        unsigned short* hr = h4 + (size_t)r * N * 64;
#pragma unroll
        for (int mt = 0; mt < 4; mt++) {
            int rowb = row0 + wave * 64 + mt * 16 + q * 4;
#pragma unroll
            for (int reg = 0; reg < 4; reg++) {
                int row = rowb + reg;
                if (row < N) {
                    short4v sv;
                    sv[0] = (short)f2bf(acc[mt][0][reg]);
                    sv[1] = (short)f2bf(acc[mt][1][reg]);
                    sv[2] = (short)f2bf(acc[mt][2][reg]);
                    sv[3] = (short)f2bf(acc[mt][3][reg]);
                    *(short4v*)&hr[(size_t)row * 64 + l15 * 4] = sv;
                }
            }
        }
    }
}

// ---------- fused MLP: Y = (tanh(X[N,320]@W1+b1))@W2 + b2; bf16 or fp32 out ----------
template <bool BFOUT>
__global__ __launch_bounds__(256, 3) void k_mlp(const unsigned short* __restrict__ X,
                                                const unsigned short* __restrict__ W1Tl,
                                                const float* __restrict__ b1,
                                                const unsigned short* __restrict__ W2Tl,
                                                const float* __restrict__ b2,
                                                unsigned short* __restrict__ Ybf,
                                                float* __restrict__ Yf, int ldy, int N) {
    __shared__ __align__(16) unsigned short Xb[256][72];
    __shared__ __align__(16) unsigned short Wb[64][72];
    int tid = threadIdx.x, wave = tid >> 6, lane = tid & 63;
    int l15 = lane & 15, q = lane >> 4;
    int row0 = blockIdx.x * 256;
    float4v acc[4][4];
#pragma unroll
    for (int mt = 0; mt < 4; mt++)
#pragma unroll
        for (int nt = 0; nt < 4; nt++) acc[mt][nt] = (float4v){0.f, 0.f, 0.f, 0.f};
    for (int kc = 0; kc < 320; kc += 64) {
        __syncthreads();
#pragma unroll
        for (int i = 0; i < 8; i++) {
            int f = tid + 256 * i;
            int rr = f >> 3, seg = f & 7;
            int grow = row0 + rr;
            short8 v = (short8){0, 0, 0, 0, 0, 0, 0, 0};
            if (grow < N) v = *(const short8*)(X + (size_t)grow * 320 + kc + seg * 8);
            *(short8*)&Xb[rr][seg * 8] = v;
        }
#pragma unroll
        for (int i = 0; i < 2; i++) {
            int f = tid + 256 * i;
            int n = f >> 3, seg = f & 7;
            *(short8*)&Wb[n][seg * 8] = *(const short8*)(W1Tl + n * 320 + kc + seg * 8);
        }
        __syncthreads();
        short8 bfr[4][2];
#pragma unroll
        for (int nt = 0; nt < 4; nt++)
#pragma unroll
            for (int ks = 0; ks < 2; ks++)
                bfr[nt][ks] = *(const short8*)&Wb[nt * 16 + l15][ks * 32 + q * 8];
#pragma unroll
        for (int mt = 0; mt < 4; mt++) {
            short8 a0 = *(const short8*)&Xb[wave * 64 + mt * 16 + l15][q * 8];
            short8 a1 = *(const short8*)&Xb[wave * 64 + mt * 16 + l15][32 + q * 8];
#pragma unroll
            for (int nt = 0; nt < 4; nt++) {
                acc[mt][nt] =
                    __builtin_amdgcn_mfma_f32_16x16x32_bf16(a0, bfr[nt][0], acc[mt][nt], 0, 0, 0);
                acc[mt][nt] =
                    __builtin_amdgcn_mfma_f32_16x16x32_bf16(a1, bfr[nt][1], acc[mt][nt], 0, 0, 0);
            }
        }
    }
    // tanh epilogue -> LDS (Xb reuse; covers all 256 rows x 64 cols exactly once)
    __syncthreads();
#pragma unroll
    for (int mt = 0; mt < 4; mt++) {
        int rlb = wave * 64 + mt * 16 + q * 4;
#pragma unroll
        for (int reg = 0; reg < 4; reg++) {
#pragma unroll
            for (int nt = 0; nt < 4; nt++) {
                int n = nt * 16 + l15;
                Xb[rlb + reg][n] = f2bf(tanhf(acc[mt][nt][reg] + b1[n]));
            }
        }
    }
    // stage W2 into Wb
#pragma unroll
    for (int i = 0; i < 2; i++) {
        int f = tid + 256 * i;
        int n = f >> 3, seg = f & 7;
        *(short8*)&Wb[n][seg * 8] = *(const short8*)(W2Tl + n * 64 + seg * 8);
    }
    __syncthreads();
    // w2 phase
    short8 bfr[4][2];
#pragma unroll
    for (int nt = 0; nt < 4; nt++)
#pragma unroll
        for (int ks = 0; ks < 2; ks++)
            bfr[nt][ks] = *(const short8*)&Wb[nt * 16 + l15][ks * 32 + q * 8];
    float4v acc2[4][4];
#pragma unroll
    for (int mt = 0; mt < 4; mt++)
#pragma unroll
        for (int nt = 0; nt < 4; nt++) acc2[mt][nt] = (float4v){0.f, 0.f, 0.f, 0.f};
#pragma unroll
    for (int mt = 0; mt < 4; mt++) {
        short8 a0 = *(const short8*)&Xb[wave * 64 + mt * 16 + l15][q * 8];
        short8 a1 = *(const short8*)&Xb[wave * 64 + mt * 16 + l15][32 + q * 8];
#pragma unroll
        for (int nt = 0; nt < 4; nt++) {
            acc2[mt][nt] =
                __builtin_amdgcn_mfma_f32_16x16x32_bf16(a0, bfr[nt][0], acc2[mt][nt], 0, 0, 0);
            acc2[mt][nt] =
                __builtin_amdgcn_mfma_f32_16x16x32_bf16(a1, bfr[nt][1], acc2[mt][nt], 0, 0, 0);
        }
    }
#pragma unroll
    for (int mt = 0; mt < 4; mt++) {
        int rowb = row0 + wave * 64 + mt * 16 + q * 4;
#pragma unroll
        for (int reg = 0; reg < 4; reg++) {
            int row = rowb + reg;
            if (row < N) {
#pragma unroll
                for (int nt = 0; nt < 4; nt++) {
                    int n = nt * 16 + l15;
                    float v = acc2[mt][nt][reg] + b2[n];
                    if (BFOUT)
                        Ybf[(size_t)row * ldy + n] = f2bf(v);
                    else
                        Yf[(size_t)row * ldy + n] = v;
                }
            }
        }
    }
}

// ---------- full-wave per-node GAT (rare fallback; gathers as_ directly) ----------
__device__ void gat_node_fullwave(int node, const int* __restrict__ csr_ptr,
                                  const int* __restrict__ csr_src,
                                  const unsigned short* __restrict__ h,
                                  const float* __restrict__ as_,
                                  const float* __restrict__ ad_, float bgv,
                                  unsigned short* __restrict__ out, int ldo, int lane) {
    float adv = ad_[node];
    float e_self = lrelu(as_[node] + adv);
    int beg = csr_ptr[node], end = csr_ptr[node + 1];
    int cnt = end - beg;

    if (cnt <= 64) {
        int s = 0;
        float e_lane = -3.0e38f;
        if (lane < cnt) {
            s = csr_src[beg + lane];
            e_lane = lrelu(as_[s] + adv);
        }
        float m = fmaxf(e_lane, e_self);
#pragma unroll
        for (int off = 32; off; off >>= 1) m = fmaxf(m, __shfl_xor(m, off));
        float p = (lane < cnt) ? expf(e_lane - m) : 0.f;
        float ssum = p;
#pragma unroll
        for (int off = 32; off; off >>= 1) ssum += __shfl_xor(ssum, off);
        float p_self = expf(e_self - m);
        float inv = 1.f / (ssum + p_self);
        float alpha = p * inv;
        float acc = p_self * inv * bf2f(h[(size_t)node * DD + lane]);
        for (int j0 = 0; j0 < cnt; ++j0) {
            int ss = __shfl(s, j0);
            float aa = __shfl(alpha, j0);
            acc += aa * bf2f(h[(size_t)ss * DD + lane]);
        }
        out[(size_t)node * ldo + lane] = f2bf(acc + bgv);
        return;
    }

    float m = e_self;
    for (int j = beg + lane; j < end; j += 64) m = fmaxf(m, lrelu(as_[csr_src[j]] + adv));
#pragma unroll
    for (int off = 32; off; off >>= 1) m = fmaxf(m, __shfl_xor(m, off));
    float ssum = 0.f;
    for (int j = beg + lane; j < end; j += 64) ssum += expf(lrelu(as_[csr_src[j]] + adv) - m);
#pragma unroll
    for (int off = 32; off; off >>= 1) ssum += __shfl_xor(ssum, off);
    ssum += expf(e_self - m);
    float inv = 1.f / ssum;
    float acc = expf(e_self - m) * inv * bf2f(h[(size_t)node * DD + lane]);
    for (int j0 = beg; j0 < end; j0 += 64) {
        int j = j0 + lane;
        int s = 0;
        float alpha = 0.f;
        if (j < end) {
            s = csr_src[j];
            alpha = expf(lrelu(as_[s] + adv) - m) * inv;
        }
        int c = end - j0;
        if (c > 64) c = 64;
        for (int t = 0; t < c; ++t) {
            int ss = __shfl(s, t);
            float aa = __shfl(alpha, t);
            acc += aa * bf2f(h[(size_t)ss * DD + lane]);
        }
    }
    out[(size_t)node * ldo + lane] = f2bf(acc + bgv);
}

// ---------- GAT: 8 nodes/wave (oct = node, 8 lanes, 8 feat/lane, uint4) ----------
// Changes vs R7 (amortization axis still pays: 103->86.5 at last doubling):
//  * 8 nodes/wave: wave count halves again (50K/dispatch); fixed chain
//    amortized over 8 nodes; slots/node ~ E[max of 8 Poisson(10)]/8 ~ 2.1.
//  * 16B uint4 gathers (8 bf16 feat/lane x 8 lanes = full 128B row per
//    node-slot): VMEM instructions per edge halved again, same coalescing.
//  * staging: up to 4 wave-uniform-guarded rounds of 8 edges/node; all s
//    staged before the as_/exp chain (R6's hoisting split preserved).
//  * LDS layout [slot][node]: reads = 8 consecutive ints across nodes
//    (conflict-free) broadcast to 8 lanes; writes <=2-way (free). Kills the
//    441K SQ_LDS_BANK_CONFLICT of R7's [node][slot] layout.
//  * 3-level reduction (offsets 4,2,1); uint4 epilogue store;
//    bias pi^-1(8lq+i) = (i&3)*16 + 2lq + (i>>2).
__global__ __launch_bounds__(256) void k_gat(const int* __restrict__ csr_ptr4,
                                             const int* __restrict__ csr_src4,
                                             const unsigned short* __restrict__ h4,
                                             const float* __restrict__ as4,
                                             const float* __restrict__ ad4,
                                             const float* __restrict__ bg4,
                                             unsigned short* __restrict__ outbase, int ldo,
                                             int N, int E) {
    __shared__ int lsa_s[4][32][8];
    __shared__ float lsa_p[4][32][8];
    int lb = blockIdx.x;
    int r = (lb & 7) >> 1;                     // relation -> XCD pair
    int idx = ((lb >> 3) << 1) + (lb & 1);     // block index within relation
    int wave = threadIdx.x >> 6, lane = threadIdx.x & 63;
    int oct = lane >> 3, lq = lane & 7;        // oct (=node), lane-in-oct
    int nodeA = idx * 32 + wave * 8;           // 32 nodes per block
    if (nodeA >= N) return;
    int node = nodeA + oct;
    bool act = node < N;

    const int* csr_ptr = csr_ptr4 + (size_t)r * (N + 1);
    const int* csr_src = csr_src4 + (size_t)r * E;
    const unsigned short* h = h4 + (size_t)r * N * 64;
    const float* as_ = as4 + (size_t)r * N;
    const float* ad_ = ad4 + (size_t)r * N;
    const float* bg = bg4 + (size_t)r * DD;
    unsigned short* out = outbase + (size_t)64 * r;

    int beg = 0, cnt = 0;
    if (act) {
        beg = csr_ptr[node];
        cnt = csr_ptr[node + 1] - beg;
    }
    int m2 = max(cnt, __shfl_xor(cnt, 8));
    m2 = max(m2, __shfl_xor(m2, 16));
    int vmax = __builtin_amdgcn_readfirstlane(max(m2, __shfl_xor(m2, 32)));

    if (vmax <= 32) {
        // ---- stage s for all rounds FIRST (enables early h-gather issue) ----
        bool in0 = lq < cnt, in1 = false, in2 = false, in3 = false;
        int s0 = in0 ? csr_src[beg + lq] : 0, s1 = 0, s2 = 0, s3 = 0;
        lsa_s[wave][lq][oct] = s0;
        if (vmax > 8) {
            in1 = (lq + 8) < cnt;
            s1 = in1 ? csr_src[beg + lq + 8] : 0;
            lsa_s[wave][lq + 8][oct] = s1;
        }
        if (vmax > 16) {
            in2 = (lq + 16) < cnt;
            s2 = in2 ? csr_src[beg + lq + 16] : 0;
            lsa_s[wave][lq + 16][oct] = s2;
        }
        if (vmax > 24) {
            in3 = (lq + 24) < cnt;
            s3 = in3 ? csr_src[beg + lq + 24] : 0;
            lsa_s[wave][lq + 24][oct] = s3;
        }
        // ---- logits: p = exp(lrelu(as_[s] + ad_[node])) (no-max softmax) ----
        float adv = act ? ad_[node] : 0.f;
        float e_self = act ? lrelu(as_[node] + adv) : 0.f;
        float p0 = in0 ? __expf(lrelu(as_[s0] + adv)) : 0.f;
        lsa_p[wave][lq][oct] = p0;
        float psum = p0;
        if (vmax > 8) {
            float p = in1 ? __expf(lrelu(as_[s1] + adv)) : 0.f;
            lsa_p[wave][lq + 8][oct] = p;
            psum += p;
        }
        if (vmax > 16) {
            float p = in2 ? __expf(lrelu(as_[s2] + adv)) : 0.f;
            lsa_p[wave][lq + 16][oct] = p;
            psum += p;
        }
        if (vmax > 24) {
            float p = in3 ? __expf(lrelu(as_[s3] + adv)) : 0.f;
            lsa_p[wave][lq + 24][oct] = p;
            psum += p;
        }
        float p_self = __expf(e_self);

        const char* hb = (const char*)h;
        unsigned lane16 = (unsigned)(lq << 4);
        uint4 hvs = make_uint4(0u, 0u, 0u, 0u);
        if (act) hvs = *(const uint4*)(hb + (((unsigned)node) << 7) + lane16);

        float a0 = 0.f, a1 = 0.f, a2 = 0.f, a3 = 0.f;
        float a4 = 0.f, a5 = 0.f, a6 = 0.f, a7 = 0.f;
        const int(*sp)[8] = &lsa_s[wave][0];
        const float(*pp)[8] = &lsa_p[wave][0];
        for (int j0 = 0; j0 < vmax; j0 += 8) {     // uniform scalar loop
#pragma unroll
            for (int g = 0; g < 2; g++) {
                if (j0 + g * 4 < vmax) {           // uniform quad guard
#pragma unroll
                    for (int u = 0; u < 4; u++) {
                        int sv = sp[j0 + g * 4 + u][oct];     // ds_read_b32
                        unsigned voff = ((unsigned)sv << 7) + lane16;
                        uint4 hv = *(const uint4*)(hb + voff);  // full 16B chunk
                        float pw = pp[j0 + g * 4 + u][oct];   // ds_read_b32
                        a0 += pw * bflo(hv.x);
                        a1 += pw * bfhi(hv.x);
                        a2 += pw * bflo(hv.y);
                        a3 += pw * bfhi(hv.y);
                        a4 += pw * bflo(hv.z);
                        a5 += pw * bfhi(hv.z);
                        a6 += pw * bflo(hv.w);
                        a7 += pw * bfhi(hv.w);
                    }
                }
            }
        }
        // 3-level within-oct reduction; overlaps the gather waits
        float ssum = psum;
#pragma unroll
        for (int off = 4; off; off >>= 1) ssum += __shfl_xor(ssum, off);
        float inv = __builtin_amdgcn_rcpf(ssum + p_self);

        if (act) {
            // features f = 8*lq + i; pi^-1(f) = (i&3)*16 + 2*lq + (i>>2)
            int b0 = 2 * lq;
            float o0 = (a0 + p_self * bflo(hvs.x)) * inv + bg[b0];
            float o1 = (a1 + p_self * bfhi(hvs.x)) * inv + bg[16 + b0];
            float o2 = (a2 + p_self * bflo(hvs.y)) * inv + bg[32 + b0];
            float o3 = (a3 + p_self * bfhi(hvs.y)) * inv + bg[48 + b0];
            float o4 = (a4 + p_self * bflo(hvs.z)) * inv + bg[b0 + 1];
            float o5 = (a5 + p_self * bfhi(hvs.z)) * inv + bg[16 + b0 + 1];
            float o6 = (a6 + p_self * bflo(hvs.w)) * inv + bg[32 + b0 + 1];
            float o7 = (a7 + p_self * bfhi(hvs.w)) * inv + bg[48 + b0 + 1];
            uint4 pck;
            pck.x = (unsigned int)f2bf(o0) | ((unsigned int)f2bf(o1) << 16);
            pck.y = (unsigned int)f2bf(o2) | ((unsigned int)f2bf(o3) << 16);
            pck.z = (unsigned int)f2bf(o4) | ((unsigned int)f2bf(o5) << 16);
            pck.w = (unsigned int)f2bf(o6) | ((unsigned int)f2bf(o7) << 16);
            *(uint4*)(out + (size_t)node * ldo + 8 * lq) = pck;
        }
        return;
    }

    // rare fallback: whole wave handles each node sequentially (proven path)
    float bgv = bg[((lane & 3) << 4) | (lane >> 2)];
#pragma unroll
    for (int k = 0; k < 8; k++) {
        if (nodeA + k < N)
            gat_node_fullwave(nodeA + k, csr_ptr, csr_src, h, as_, ad_, bgv, out, ldo, lane);
    }
}

extern "C" void kernel_launch(void* const* d_in, const int* in_sizes, int n_in,
                              void* d_out, int out_size, void* d_ws, size_t ws_size,
                              hipStream_t stream) {
    const float* x = (const float*)d_in[0];
    const int* edges = (const int*)d_in[1];
    const float* Wg = (const float*)d_in[2];
    const float* a_src = (const float*)d_in[3];
    const float* a_dst = (const float*)d_in[4];
    const float* bg = (const float*)d_in[5];
    const float* W1 = (const float*)d_in[6];
    const float* b1 = (const float*)d_in[7];
    const float* W2 = (const float*)d_in[8];
    const float* b2 = (const float*)d_in[9];
    float* out = (float*)d_out;

    const int N = in_sizes[0] / DD;          // 100000
    const int E = in_sizes[1] / (2 * RREL);  // 1000000
    const int NB = (N + BSZ - 1) >> BSH;     // 98 buckets (requires N <= 131072)

    // workspace layout (256B aligned)
    size_t off = 0;
    auto alloc = [&](size_t bytes) {
        size_t o = off;
        off = (off + bytes + 255) & ~(size_t)255;
        return o;
    };
    char* ws = (char*)d_ws;
    unsigned short* combined = (unsigned short*)(ws + alloc((size_t)N * 320 * 2));  // bf16
    unsigned short* h4 = (unsigned short*)(ws + alloc((size_t)4 * N * 64 * 2));
    float* wsrc = (float*)(ws + alloc(LLAY * RREL * DD * 4));
    float* wdst = (float*)(ws + alloc(LLAY * RREL * DD * 4));
    unsigned short* WgT = (unsigned short*)(ws + alloc(8 * 4096 * 2));
    unsigned short* W1T = (unsigned short*)(ws + alloc(2 * 64 * 320 * 2));
    unsigned short* W2T = (unsigned short*)(ws + alloc(2 * 4096 * 2));
    int* btot = (int*)(ws + alloc((size_t)RREL * NB * 4));
    int* bucketoff = (int*)(ws + alloc((size_t)RREL * (NB + 1) * 4));
    int* bpos = (int*)(ws + alloc((size_t)RREL * NB * 4));
    unsigned int* packed = (unsigned int*)(ws + alloc((size_t)RREL * E * 4));  // also as4/ad4
    int* csr_ptr = (int*)(ws + alloc((size_t)RREL * (N + 1) * 4));
    int* csr_src = (int*)(ws + alloc((size_t)RREL * E * 4));
    (void)ws_size;
    float* as4 = (float*)packed;  // packed dead after CSR build
    float* ad4 = as4 + (size_t)4 * N;

    const int ebblocks = (E + EPB - 1) / EPB;

    // --- preprocessing ---
    k_zero<<<dim3((RREL * NB + 255) / 256), dim3(256), 0, stream>>>(btot, RREL * NB);
    k_wvec<<<dim3(2), dim3(256), 0, stream>>>(Wg, a_src, a_dst, wsrc, wdst);
    k_prep<<<dim3(320), dim3(256), 0, stream>>>(Wg, W1, W2, WgT, W1T, W2T);
    k_copy_x<<<dim3((N * 32 + 255) / 256), dim3(256), 0, stream>>>(x, combined, N);
    k_bhist<<<dim3(ebblocks, RREL), dim3(256), 0, stream>>>(edges, btot, E, NB);
    k_bscan<<<dim3(1), dim3(64), 0, stream>>>(btot, bucketoff, bpos, csr_ptr, N, E, NB);
    k_binscatter<<<dim3(ebblocks, RREL), dim3(256), 0, stream>>>(edges, bpos, packed, E, NB);
    k_bucket_sort<<<dim3(NB, RREL), dim3(256), 0, stream>>>(packed, bucketoff, csr_ptr, csr_src,
                                                            N, E, NB);

    const int gemm_blocks = (N + 255) / 256;
    // k_gat: 32 nodes/block (8 nodes/wave); grid = 8 * ceil(bpr/2) so lb%8
    // encodes {relation pair -> XCD} and covers all (r, idx) pairs.
    const int bpr = (N + 31) / 32;
    const int gat_grid = 8 * ((bpr + 1) / 2);

    for (int l = 0; l < LLAY; l++) {
        k_hgemm<<<dim3(gemm_blocks), dim3(256), 0, stream>>>(
            combined, WgT + (size_t)l * 4 * 4096, wsrc + l * 256, wdst + l * 256, h4, as4, ad4, N);
        k_gat<<<dim3(gat_grid), dim3(256), 0, stream>>>(
            csr_ptr, csr_src, h4, as4, ad4, bg + (size_t)l * RREL * DD,
            combined + 64, 320, N, E);
        if (l == LLAY - 1) {
            k_mlp<false><<<dim3(gemm_blocks), dim3(256), 0, stream>>>(
                combined, W1T + (size_t)l * 20480, b1 + l * DD, W2T + (size_t)l * 4096,
                b2 + l * DD, nullptr, out, DD, N);
        } else {
            k_mlp<true><<<dim3(gemm_blocks), dim3(256), 0, stream>>>(
                combined, W1T + (size_t)l * 20480, b1 + l * DD, W2T + (size_t)l * 4096,
                b2 + l * DD, combined, nullptr, 320, N);
        }
    }
}